// Round 10
// baseline (3267.723 us; speedup 1.0000x reference)
//
#include <hip/hip_runtime.h>
#include <hip/hip_bf16.h>

#define BATCH 64
#define NPIX 196
#define ENCD 2048
#define ATTD 512
#define DECD 512
#define EMBD 512
#define NVOCAB 10000
#define TSTEPS 24
#define KX 3072
#define NPAD 10112

typedef short bf16x8 __attribute__((ext_vector_type(8)));
typedef float f32x4 __attribute__((ext_vector_type(4)));

__device__ inline ushort f2bf(float f) {
    union { float f; unsigned u; } v; v.f = f;
    unsigned r = (v.u + 0x7fff + ((v.u >> 16) & 1)) >> 16;
    return (ushort)r;
}
__device__ inline float bf2f(ushort u) {
    union { unsigned u; float f; } v; v.u = ((unsigned)u) << 16;
    return v.f;
}

// ================= fused one-time prep =================
__global__ __launch_bounds__(256) void k_prep(
        const float* __restrict__ Wih, const float* __restrict__ Whh,
        const float* __restrict__ Wd, const float* __restrict__ Wfb,
        const float* __restrict__ Wfc, const float* __restrict__ We,
        const float* __restrict__ emb, const int* __restrict__ caps,
        const int* __restrict__ lens,
        ushort* __restrict__ WTj, ushort* __restrict__ BpreT,
        ushort* __restrict__ WfcT, ushort* __restrict__ WeT,
        ushort* __restrict__ embpartb, float* __restrict__ hcacc,
        float* __restrict__ cap_out, float* __restrict__ len_out) {
    __shared__ float tile[32][33];
    int blk = blockIdx.x, tid = threadIdx.x;
    if (blk < 2048) {
        int j = blk;
        // columns [0,512) of WTj are never read (emb handled via embpart) — skip
        for (int k = 512 + tid; k < KX; k += 256) {
            float v = (k < 2560) ? Wih[(size_t)j * 2560 + k] : Whh[(size_t)j * 512 + (k - 2560)];
            WTj[(size_t)j * KX + k] = f2bf(v);
        }
        if (blk == 0) {
            for (int i = tid; i < 1664; i += 256) {
                if (i < 1600) cap_out[i] = (float)caps[i];
                else          len_out[i - 1600] = (float)(lens[i - 1600] - 1);
            }
        }
    } else if (blk < 3328) {
        int i = blk - 2048;
        int nb = (i % 80) * 32, kb = (i / 80) * 32;
        int tx = tid & 31, ty = tid >> 5;
        for (int s = 0; s < 32; s += 8) {
            int k = kb + ty + s, n = nb + tx;
            float v = (n < ATTD) ? Wd[(size_t)k * ATTD + n] : Wfb[(size_t)k * ENCD + (n - ATTD)];
            tile[ty + s][tx] = v;
        }
        __syncthreads();
        for (int s = 0; s < 32; s += 8)
            BpreT[(size_t)(nb + ty + s) * 512 + kb + tx] = f2bf(tile[tx][ty + s]);
    } else if (blk < 8384) {
        int i = blk - 3328;
        int nb = (i % 316) * 32, kb = (i / 316) * 32;
        int tx = tid & 31, ty = tid >> 5;
        for (int s = 0; s < 32; s += 8) {
            int k = kb + ty + s, n = nb + tx;
            float v = (n < NVOCAB) ? Wfc[(size_t)k * NVOCAB + n] : 0.f;
            tile[ty + s][tx] = v;
        }
        __syncthreads();
        for (int s = 0; s < 32; s += 8)
            WfcT[(size_t)(nb + ty + s) * 512 + kb + tx] = f2bf(tile[tx][ty + s]);
    } else if (blk < 9408) {
        int i = blk - 8384;
        int nb = (i % 16) * 32, kb = (i / 16) * 32;
        int tx = tid & 31, ty = tid >> 5;
        for (int s = 0; s < 32; s += 8) {
            int k = kb + ty + s, n = nb + tx;
            tile[ty + s][tx] = We[(size_t)k * ATTD + n];
        }
        __syncthreads();
        for (int s = 0; s < 32; s += 8)
            WeT[(size_t)(nb + ty + s) * ENCD + kb + tx] = f2bf(tile[tx][ty + s]);
    } else if (blk < 10176) {
        int i = blk - 9408;
        int r0 = (i % 24) * 64;
        int n0 = (i / 24) * 64;
        int w = tid >> 6, l = tid & 63;
        int m = l & 15, kg = l >> 4;
        int n = n0 + w * 16 + m;
        const float* Bp = Wih + (size_t)n * 2560 + kg * 8;
        int tok[4];
#pragma unroll
        for (int mf = 0; mf < 4; ++mf) {
            int row = r0 + m + mf * 16;
            tok[mf] = caps[(row & 63) * 25 + (row >> 6)];
        }
        f32x4 acc[4] = {};
        for (int k0 = 0; k0 < 512; k0 += 32) {
            float4 b0 = *(const float4*)(Bp + k0);
            float4 b1 = *(const float4*)(Bp + k0 + 4);
            bf16x8 bb;
            bb[0] = f2bf(b0.x); bb[1] = f2bf(b0.y); bb[2] = f2bf(b0.z); bb[3] = f2bf(b0.w);
            bb[4] = f2bf(b1.x); bb[5] = f2bf(b1.y); bb[6] = f2bf(b1.z); bb[7] = f2bf(b1.w);
#pragma unroll
            for (int mf = 0; mf < 4; ++mf) {
                const float* ap = emb + (size_t)tok[mf] * 512 + kg * 8 + k0;
                float4 f0 = *(const float4*)ap;
                float4 f1 = *(const float4*)(ap + 4);
                bf16x8 a;
                a[0] = f2bf(f0.x); a[1] = f2bf(f0.y); a[2] = f2bf(f0.z); a[3] = f2bf(f0.w);
                a[4] = f2bf(f1.x); a[5] = f2bf(f1.y); a[6] = f2bf(f1.z); a[7] = f2bf(f1.w);
                acc[mf] = __builtin_amdgcn_mfma_f32_16x16x32_bf16(a, bb, acc[mf], 0, 0, 0);
            }
        }
#pragma unroll
        for (int mf = 0; mf < 4; ++mf)
#pragma unroll
            for (int r = 0; r < 4; ++r)
                embpartb[(size_t)(r0 + mf * 16 + kg * 4 + r) * 2048 + n] = f2bf(acc[mf][r]);
    } else {
        int i = blk - 10176;
        for (int j = tid; j < 2048; j += 256) hcacc[(size_t)i * 2048 + j] = 0.f;
    }
}

// ---------------- enc fp32 -> bf16 ----------------
__global__ void k_encconv(const float* __restrict__ enc, ushort* __restrict__ encb) {
    size_t i = ((size_t)blockIdx.x * 256 + threadIdx.x) * 8;
    float4 f0 = *(const float4*)(enc + i);
    float4 f1 = *(const float4*)(enc + i + 4);
    union { bf16x8 v; ushort u[8]; } o;
    o.u[0] = f2bf(f0.x); o.u[1] = f2bf(f0.y); o.u[2] = f2bf(f0.z); o.u[3] = f2bf(f0.w);
    o.u[4] = f2bf(f1.x); o.u[5] = f2bf(f1.y); o.u[6] = f2bf(f1.z); o.u[7] = f2bf(f1.w);
    *(bf16x8*)(encb + i) = o.v;
}

// ---------------- mean over 196 positions ----------------
__global__ __launch_bounds__(256) void k_meanb(const ushort* __restrict__ encb,
                                               ushort* __restrict__ meanb) {
    int b = blockIdx.x, half = blockIdx.y;
    int e0 = half * 1024 + threadIdx.x * 4;
    const ushort* ep = encb + (size_t)b * NPIX * ENCD + e0;
    float s0 = 0.f, s1 = 0.f, s2 = 0.f, s3 = 0.f;
#pragma unroll 4
    for (int p = 0; p < NPIX; ++p) {
        ushort4 v = *(const ushort4*)(ep + (size_t)p * ENCD);
        s0 += bf2f(v.x); s1 += bf2f(v.y); s2 += bf2f(v.z); s3 += bf2f(v.w);
    }
    const float sc = 1.0f / NPIX;
    ushort4 o;
    o.x = f2bf(s0 * sc); o.y = f2bf(s1 * sc); o.z = f2bf(s2 * sc); o.w = f2bf(s3 * sc);
    *(ushort4*)(meanb + (size_t)b * ENCD + e0) = o;
}

// ---------------- h0/c0 init partials ----------------
__global__ __launch_bounds__(256) void k_initp(
        const ushort* __restrict__ meanb,
        const float* __restrict__ Wh, const float* __restrict__ Wc,
        float* __restrict__ hcacc) {
    __shared__ float mm[4][256];
    int bg = blockIdx.x * 4;
    int jy = blockIdx.y;
    int kz = blockIdx.z;
    int tid = threadIdx.x;
    for (int i = tid; i < 1024; i += 256) {
        int qq = i >> 8, k = i & 255;
        mm[qq][k] = bf2f(meanb[(size_t)(bg + qq) * ENCD + kz * 256 + k]);
    }
    __syncthreads();
    int j = jy * 256 + tid;
    const float* W; int col;
    if (j < 512) { W = Wh; col = j; } else { W = Wc; col = j - 512; }
    W += (size_t)(kz * 256) * 512 + col;
    float acc[4] = {};
    for (int k = 0; k < 256; ++k) {
        float w = W[(size_t)k * 512];
#pragma unroll
        for (int qq = 0; qq < 4; ++qq) acc[qq] += mm[qq][k] * w;
    }
#pragma unroll
    for (int qq = 0; qq < 4; ++qq)
        atomicAdd(hcacc + (size_t)(bg + qq) * 1024 + j, acc[qq]);
}

__global__ __launch_bounds__(256) void k_initfin(
        const float* __restrict__ hcacc, const float* __restrict__ bh,
        const float* __restrict__ bc, ushort* __restrict__ hbf,
        float* __restrict__ c) {
    int base = blockIdx.x * 2048;
    for (int i = threadIdx.x; i < 2048; i += 256) {
        int idx = base + i;
        int b = idx >> 10, n = idx & 1023;
        float v = hcacc[idx];
        if (n < 512) hbf[(size_t)b * 512 + n] = f2bf(v + bh[n]);
        else         c[(size_t)b * 512 + (n - 512)] = v + bc[n - 512];
    }
}

// ---------------- one-time: att1 = enc @ We + be ----------------
__global__ __launch_bounds__(256) void k_att1(
        const ushort* __restrict__ encb, const ushort* __restrict__ WeT,
        const float* __restrict__ be, ushort* __restrict__ att1b) {
    int w = threadIdx.x >> 6, l = threadIdx.x & 63;
    int wr = w >> 1, wc = w & 1;
    int m0 = blockIdx.x * 128 + wr * 64;
    int n0 = blockIdx.y * 128 + wc * 64;
    int ml = l & 15, kg = l >> 4;
    const ushort* aBase = encb + (size_t)(m0 + ml) * ENCD + kg * 8;
    const ushort* bBase = WeT + (size_t)(n0 + ml) * ENCD + kg * 8;
    f32x4 acc[4][4] = {};
    for (int k0 = 0; k0 < ENCD; k0 += 32) {
        bf16x8 bfr[4], afr[4];
#pragma unroll
        for (int nf = 0; nf < 4; ++nf)
            bfr[nf] = *(const bf16x8*)(bBase + (size_t)nf * 16 * ENCD + k0);
#pragma unroll
        for (int mf = 0; mf < 4; ++mf)
            afr[mf] = *(const bf16x8*)(aBase + (size_t)mf * 16 * ENCD + k0);
#pragma unroll
        for (int mf = 0; mf < 4; ++mf)
#pragma unroll
            for (int nf = 0; nf < 4; ++nf)
                acc[mf][nf] = __builtin_amdgcn_mfma_f32_16x16x32_bf16(afr[mf], bfr[nf], acc[mf][nf], 0, 0, 0);
    }
#pragma unroll
    for (int mf = 0; mf < 4; ++mf)
#pragma unroll
        for (int nf = 0; nf < 4; ++nf) {
            int col = n0 + nf * 16 + ml;
            float bias = be[col];
#pragma unroll
            for (int r = 0; r < 4; ++r) {
                int row = m0 + mf * 16 + kg * 4 + r;
                att1b[(size_t)row * ATTD + col] = f2bf(acc[mf][nf][r] + bias);
            }
        }
}

// ---------------- per-step K1: batched-MFMA att2+gate (redundant) + softmax + ctx ----------------
// 256 blocks (b,q): each block computes the FULL 64x512 att2 GEMM + its 64x512 gate-quarter
// GEMM via MFMA (cheap, ~0.5 GF total) and extracts row b from the C fragments into LDS.
__global__ __launch_bounds__(512) void k_attctx2(
        const ushort* __restrict__ hb_cur, const ushort* __restrict__ att1b,
        const ushort* __restrict__ encb, const ushort* __restrict__ BpreT,
        const float* __restrict__ vatt, const float* __restrict__ bv,
        const float* __restrict__ bd, const float* __restrict__ bfb,
        const int* __restrict__ lens,
        ushort* __restrict__ ctxb, float* __restrict__ alpha_out, int t) {
    __shared__ float att2_lds[512];
    __shared__ float gate_lds[512];
    __shared__ float ev[200];
    __shared__ float cpart[4][512];
    __shared__ float inv_s;
    int bid = blockIdx.x;
    int b = bid >> 2, q = bid & 3;
    int tid = threadIdx.x;
    int w = tid >> 6, l = tid & 63;
    int m = l & 15, kg = l >> 4;

    // ---- phase 0: att2 (n-slice w*64) + gate-quarter (same slice), extract row b ----
    {
        int n0w = w * 64;
        const ushort* A = hb_cur + (size_t)m * 512 + kg * 8;
        int kgb = (b & 15) >> 2, mfb = b >> 4, rb = b & 3;
        {
            f32x4 acc[4][4] = {};
            const ushort* B = BpreT + (size_t)(n0w + m) * 512 + kg * 8;
#pragma unroll 4
            for (int k0 = 0; k0 < 512; k0 += 32) {
                bf16x8 bfr[4];
#pragma unroll
                for (int nf = 0; nf < 4; ++nf)
                    bfr[nf] = *(const bf16x8*)(B + (size_t)nf * 16 * 512 + k0);
#pragma unroll
                for (int mf = 0; mf < 4; ++mf) {
                    bf16x8 afr = *(const bf16x8*)(A + (size_t)mf * 16 * 512 + k0);
#pragma unroll
                    for (int nf = 0; nf < 4; ++nf)
                        acc[mf][nf] = __builtin_amdgcn_mfma_f32_16x16x32_bf16(afr, bfr[nf], acc[mf][nf], 0, 0, 0);
                }
            }
            if (kg == kgb) {
#pragma unroll
                for (int nf = 0; nf < 4; ++nf) {
                    int n = n0w + nf * 16 + m;
                    att2_lds[n] = acc[mfb][nf][rb] + bd[n];
                }
            }
        }
        {
            f32x4 acc[4][4] = {};
            const ushort* B = BpreT + (size_t)(512 + q * 512 + n0w + m) * 512 + kg * 8;
#pragma unroll 4
            for (int k0 = 0; k0 < 512; k0 += 32) {
                bf16x8 bfr[4];
#pragma unroll
                for (int nf = 0; nf < 4; ++nf)
                    bfr[nf] = *(const bf16x8*)(B + (size_t)nf * 16 * 512 + k0);
#pragma unroll
                for (int mf = 0; mf < 4; ++mf) {
                    bf16x8 afr = *(const bf16x8*)(A + (size_t)mf * 16 * 512 + k0);
#pragma unroll
                    for (int nf = 0; nf < 4; ++nf)
                        acc[mf][nf] = __builtin_amdgcn_mfma_f32_16x16x32_bf16(afr, bfr[nf], acc[mf][nf], 0, 0, 0);
                }
            }
            if (kg == kgb) {
#pragma unroll
                for (int nf = 0; nf < 4; ++nf) {
                    int n = n0w + nf * 16 + m;
                    int e = q * 512 + n;
                    gate_lds[n] = 1.f / (1.f + __expf(-(acc[mfb][nf][rb] + bfb[e])));
                }
            }
        }
    }
    __syncthreads();

    // ---- phase 1: scores (8 waves over 196 pixels) ----
    {
        float a2r[8], vvr[8];
#pragma unroll
        for (int i = 0; i < 8; ++i) {
            a2r[i] = att2_lds[l * 8 + i];
            vvr[i] = vatt[l * 8 + i];
        }
        float bv0 = bv[0];
        for (int pp = w; pp < NPIX; pp += 8) {
            bf16x8 f = *(const bf16x8*)(att1b + ((size_t)b * NPIX + pp) * ATTD + l * 8);
            float s = 0.f;
#pragma unroll
            for (int i = 0; i < 8; ++i)
                s += fmaxf(bf2f((ushort)f[i]) + a2r[i], 0.f) * vvr[i];
            for (int off = 32; off > 0; off >>= 1) s += __shfl_down(s, off);
            if (l == 0) ev[pp] = s + bv0;
        }
    }
    __syncthreads();
    if (w == 0) {
        float mx = -1e30f;
        for (int pp = l; pp < NPIX; pp += 64) mx = fmaxf(mx, ev[pp]);
        for (int off = 32; off > 0; off >>= 1) mx = fmaxf(mx, __shfl_down(mx, off));
        mx = __shfl(mx, 0);
        float s = 0.f;
        for (int pp = l; pp < NPIX; pp += 64) {
            float e_ = __expf(ev[pp] - mx);
            ev[pp] = e_;
            s += e_;
        }
        for (int off = 32; off > 0; off >>= 1) s += __shfl_down(s, off);
        if (l == 0) inv_s = 1.0f / s;
    }
    __syncthreads();
    float inv = inv_s;
    if (q == 0 && tid < NPIX) {
        bool active = t < (lens[b] - 1);
        alpha_out[((size_t)b * TSTEPS + t) * NPIX + tid] = active ? ev[tid] * inv : 0.f;
    }
    // ---- phase 2: ctx quarter (4-way p-split) ----
    {
        int pg = tid >> 7, th = tid & 127;
        const ushort* ep = encb + (size_t)b * NPIX * ENCD + q * 512 + th * 4;
        float s0 = 0.f, s1 = 0.f, s2 = 0.f, s3 = 0.f;
        for (int pp = pg; pp < NPIX; pp += 4) {
            ushort4 v = *(const ushort4*)(ep + (size_t)pp * ENCD);
            float al = ev[pp];
            s0 += al * bf2f(v.x); s1 += al * bf2f(v.y);
            s2 += al * bf2f(v.z); s3 += al * bf2f(v.w);
        }
        cpart[pg][th * 4 + 0] = s0;
        cpart[pg][th * 4 + 1] = s1;
        cpart[pg][th * 4 + 2] = s2;
        cpart[pg][th * 4 + 3] = s3;
    }
    __syncthreads();
    if (tid < 128) {
        ushort4 o;
        float g0 = gate_lds[tid * 4 + 0], g1 = gate_lds[tid * 4 + 1];
        float g2 = gate_lds[tid * 4 + 2], g3 = gate_lds[tid * 4 + 3];
        o.x = f2bf((cpart[0][tid * 4 + 0] + cpart[1][tid * 4 + 0] + cpart[2][tid * 4 + 0] + cpart[3][tid * 4 + 0]) * inv * g0);
        o.y = f2bf((cpart[0][tid * 4 + 1] + cpart[1][tid * 4 + 1] + cpart[2][tid * 4 + 1] + cpart[3][tid * 4 + 1]) * inv * g1);
        o.z = f2bf((cpart[0][tid * 4 + 2] + cpart[1][tid * 4 + 2] + cpart[2][tid * 4 + 2] + cpart[3][tid * 4 + 2]) * inv * g2);
        o.w = f2bf((cpart[0][tid * 4 + 3] + cpart[1][tid * 4 + 3] + cpart[2][tid * 4 + 3] + cpart[3][tid * 4 + 3]) * inv * g3);
        *(ushort4*)(ctxb + (size_t)b * 2048 + q * 512 + tid * 4) = o;
    }
}

// ---------------- per-step K2: gates GEMM (128 blocks, K=2560=[ctx|h]) + LSTM ----------------
__global__ __launch_bounds__(512) void k_gates2(
        const ushort* __restrict__ ctxb, const ushort* __restrict__ hb_cur,
        const ushort* __restrict__ WTj, const ushort* __restrict__ embpartb,
        const float* __restrict__ bih, const float* __restrict__ bhh,
        const int* __restrict__ lens, float* __restrict__ c,
        ushort* __restrict__ hb_nxt, ushort* __restrict__ hAll, int t) {
    __shared__ float part[8][64][16];
    int g = blockIdx.x;
    int tid = threadIdx.x;
    int w = tid >> 6, l = tid & 63;
    int m = l & 15, kg = l >> 4;
    int jrow = (m >> 2) * 512 + g * 4 + (m & 3);
    const ushort* Brow = WTj + (size_t)jrow * KX;
    f32x4 acc[4] = {};
    {
        const ushort* B = Brow + 512 + w * 256 + kg * 8;
        const ushort* A = ctxb + (size_t)m * 2048 + w * 256 + kg * 8;
#pragma unroll
        for (int k0 = 0; k0 < 256; k0 += 32) {
            bf16x8 bfr = *(const bf16x8*)(B + k0);
#pragma unroll
            for (int mf = 0; mf < 4; ++mf) {
                bf16x8 afr = *(const bf16x8*)(A + (size_t)mf * 16 * 2048 + k0);
                acc[mf] = __builtin_amdgcn_mfma_f32_16x16x32_bf16(afr, bfr, acc[mf], 0, 0, 0);
            }
        }
    }
    if (w < 2) {
        const ushort* B = Brow + 2560 + w * 256 + kg * 8;
        const ushort* A = hb_cur + (size_t)m * 512 + w * 256 + kg * 8;
#pragma unroll
        for (int k0 = 0; k0 < 256; k0 += 32) {
            bf16x8 bfr = *(const bf16x8*)(B + k0);
#pragma unroll
            for (int mf = 0; mf < 4; ++mf) {
                bf16x8 afr = *(const bf16x8*)(A + (size_t)mf * 16 * 512 + k0);
                acc[mf] = __builtin_amdgcn_mfma_f32_16x16x32_bf16(afr, bfr, acc[mf], 0, 0, 0);
            }
        }
    }
#pragma unroll
    for (int mf = 0; mf < 4; ++mf)
#pragma unroll
        for (int r = 0; r < 4; ++r)
            part[w][mf * 16 + kg * 4 + r][m] = acc[mf][r];
    __syncthreads();
    if (tid < 256) {
        int bb = tid >> 2, j = tid & 3;
        int d = g * 4 + j;
        float gi = 0.f, gf = 0.f, gg = 0.f, go = 0.f;
#pragma unroll
        for (int w8 = 0; w8 < 8; ++w8) {
            gi += part[w8][bb][j];
            gf += part[w8][bb][4 + j];
            gg += part[w8][bb][8 + j];
            go += part[w8][bb][12 + j];
        }
        ushort hout = hb_cur[(size_t)bb * 512 + d];
        if (t < lens[bb] - 1) {
            const ushort* eb = embpartb + ((size_t)t * 64 + bb) * 2048;
            gi += bf2f(eb[d])        + bih[d]        + bhh[d];
            gf += bf2f(eb[512 + d])  + bih[512 + d]  + bhh[512 + d];
            gg += bf2f(eb[1024 + d]) + bih[1024 + d] + bhh[1024 + d];
            go += bf2f(eb[1536 + d]) + bih[1536 + d] + bhh[1536 + d];
            float cc = c[(size_t)bb * 512 + d];
            float si = 1.f / (1.f + __expf(-gi));
            float sf = 1.f / (1.f + __expf(-gf));
            float so = 1.f / (1.f + __expf(-go));
            float cn = sf * cc + si * tanhf(gg);
            float hn = so * tanhf(cn);
            c[(size_t)bb * 512 + d] = cn;
            hout = f2bf(hn);
        }
        hb_nxt[(size_t)bb * 512 + d] = hout;
        hAll[((size_t)t * 64 + bb) * 512 + d] = hout;
    }
}

// ---------------- post-loop: pred = hAll @ WfcT + bfc (masked) ----------------
__global__ __launch_bounds__(256) void k_predall(
        const ushort* __restrict__ hAll, const ushort* __restrict__ WfcT,
        const float* __restrict__ bfc, const int* __restrict__ lens,
        float* __restrict__ pred) {
    int w = threadIdx.x >> 6, l = threadIdx.x & 63;
    int wr = w >> 1, wc = w & 1;
    int m0 = blockIdx.x * 128 + wr * 64;
    int n0 = blockIdx.y * 128 + wc * 64;
    int ml = l & 15, kg = l >> 4;
    const ushort* aBase = hAll + (size_t)(m0 + ml) * 512 + kg * 8;
    const ushort* bBase = WfcT + (size_t)(n0 + ml) * 512 + kg * 8;
    f32x4 acc[4][4] = {};
#pragma unroll 2
    for (int k0 = 0; k0 < 512; k0 += 32) {
        bf16x8 bfr[4], afr[4];
#pragma unroll
        for (int nf = 0; nf < 4; ++nf)
            bfr[nf] = *(const bf16x8*)(bBase + (size_t)nf * 16 * 512 + k0);
#pragma unroll
        for (int mf = 0; mf < 4; ++mf)
            afr[mf] = *(const bf16x8*)(aBase + (size_t)mf * 16 * 512 + k0);
#pragma unroll
        for (int mf = 0; mf < 4; ++mf)
#pragma unroll
            for (int nf = 0; nf < 4; ++nf)
                acc[mf][nf] = __builtin_amdgcn_mfma_f32_16x16x32_bf16(afr[mf], bfr[nf], acc[mf][nf], 0, 0, 0);
    }
#pragma unroll
    for (int mf = 0; mf < 4; ++mf)
#pragma unroll
        for (int nf = 0; nf < 4; ++nf) {
            int col = n0 + nf * 16 + ml;
            if (col < NVOCAB) {
                float bias = bfc[col];
#pragma unroll
                for (int r = 0; r < 4; ++r) {
                    int row = m0 + mf * 16 + kg * 4 + r;
                    int t = row >> 6, b = row & 63;
                    bool act = t < (lens[b] - 1);
                    pred[((size_t)b * TSTEPS + t) * NVOCAB + col] = act ? acc[mf][nf][r] + bias : 0.f;
                }
            }
        }
}

extern "C" void kernel_launch(void* const* d_in, const int* in_sizes, int n_in,
                              void* d_out, int out_size, void* d_ws, size_t ws_size,
                              hipStream_t stream) {
    const float* enc  = (const float*)d_in[0];
    const int*   caps = (const int*)d_in[1];
    const int*   lens = (const int*)d_in[2];
    const float* emb  = (const float*)d_in[3];
    const float* We   = (const float*)d_in[4];
    const float* be   = (const float*)d_in[5];
    const float* Wd   = (const float*)d_in[6];
    const float* bd   = (const float*)d_in[7];
    const float* vatt = (const float*)d_in[8];
    const float* bv   = (const float*)d_in[9];
    const float* Wih  = (const float*)d_in[10];
    const float* bih  = (const float*)d_in[11];
    const float* Whh  = (const float*)d_in[12];
    const float* bhh  = (const float*)d_in[13];
    const float* Winh = (const float*)d_in[14];
    const float* binh = (const float*)d_in[15];
    const float* Winc = (const float*)d_in[16];
    const float* binc = (const float*)d_in[17];
    const float* Wfb  = (const float*)d_in[18];
    const float* bfb  = (const float*)d_in[19];
    const float* Wfc  = (const float*)d_in[20];
    const float* bfc  = (const float*)d_in[21];

    float* out       = (float*)d_out;
    float* pred_out  = out;
    float* cap_out   = out + 15360000;
    float* len_out   = out + 15361600;
    float* alpha_out = out + 15361664;

    char* p = (char*)d_ws;
    ushort* att1b    = (ushort*)p; p += (size_t)12544 * 512 * 2;
    ushort* WTj      = (ushort*)p; p += (size_t)2048 * KX * 2;
    ushort* WfcT     = (ushort*)p; p += (size_t)NPAD * 512 * 2;
    ushort* BpreT    = (ushort*)p; p += (size_t)2560 * 512 * 2;
    ushort* WeT      = (ushort*)p; p += (size_t)512 * 2048 * 2;
    ushort* embpartb = (ushort*)p; p += (size_t)1536 * 2048 * 2;
    ushort* hAll     = (ushort*)p; p += (size_t)1536 * 512 * 2;
    ushort* ctxb     = (ushort*)p; p += (size_t)64 * 2048 * 2;   // aliased: hcacc
    ushort* hb0      = (ushort*)p; p += (size_t)64 * 512 * 2;
    ushort* hb1      = (ushort*)p; p += (size_t)64 * 512 * 2;
    float* c         = (float*)p;  p += (size_t)64 * 512 * 4;
    ushort* meanb    = (ushort*)p; p += (size_t)64 * 2048 * 2;
    ushort* encb     = (ushort*)p; p += (size_t)64 * NPIX * ENCD * 2;
    float* hcacc     = (float*)ctxb;

    k_prep<<<10208, 256, 0, stream>>>(Wih, Whh, Wd, Wfb, Wfc, We, emb, caps, lens,
                                      WTj, BpreT, WfcT, WeT, embpartb, hcacc,
                                      cap_out, len_out);
    k_encconv<<<12544, 256, 0, stream>>>(enc, encb);
    k_meanb<<<dim3(64, 2), 256, 0, stream>>>(encb, meanb);
    k_initp<<<dim3(16, 4, 8), 256, 0, stream>>>(meanb, Winh, Winc, hcacc);
    k_initfin<<<32, 256, 0, stream>>>(hcacc, binh, binc, hb0, c);
    k_att1<<<dim3(98, 4), 256, 0, stream>>>(encb, WeT, be, att1b);

    for (int t = 0; t < TSTEPS; ++t) {
        const ushort* hcur = (t & 1) ? hb1 : hb0;
        ushort* hnxt = (t & 1) ? hb0 : hb1;
        k_attctx2<<<256, 512, 0, stream>>>(hcur, att1b, encb, BpreT, vatt, bv,
                                           bd, bfb, lens, ctxb, alpha_out, t);
        k_gates2<<<128, 512, 0, stream>>>(ctxb, hcur, WTj, embpartb, bih, bhh,
                                          lens, c, hnxt, hAll, t);
    }
    k_predall<<<dim3(12, 79), 256, 0, stream>>>(hAll, WfcT, bfc, lens, pred_out);
}

// Round 11
// 1809.549 us; speedup vs baseline: 1.8058x; 1.8058x over previous
//
#include <hip/hip_runtime.h>
#include <hip/hip_bf16.h>

#define BATCH 64
#define NPIX 196
#define ENCD 2048
#define ATTD 512
#define DECD 512
#define EMBD 512
#define NVOCAB 10000
#define TSTEPS 24
#define KX 3072
#define NPAD 10112

typedef short bf16x8 __attribute__((ext_vector_type(8)));
typedef float f32x4 __attribute__((ext_vector_type(4)));

__device__ inline ushort f2bf(float f) {
    union { float f; unsigned u; } v; v.f = f;
    unsigned r = (v.u + 0x7fff + ((v.u >> 16) & 1)) >> 16;
    return (ushort)r;
}
__device__ inline float bf2f(ushort u) {
    union { unsigned u; float f; } v; v.u = ((unsigned)u) << 16;
    return v.f;
}

// ================= fused one-time prep =================
__global__ __launch_bounds__(256) void k_prep(
        const float* __restrict__ Wih, const float* __restrict__ Whh,
        const float* __restrict__ Wd, const float* __restrict__ Wfb,
        const float* __restrict__ Wfc, const float* __restrict__ We,
        const float* __restrict__ emb, const int* __restrict__ caps,
        const int* __restrict__ lens,
        ushort* __restrict__ WTj, ushort* __restrict__ BpreT,
        ushort* __restrict__ WfcT, ushort* __restrict__ WeT,
        ushort* __restrict__ embpartb, float* __restrict__ hcacc,
        float* __restrict__ cap_out, float* __restrict__ len_out) {
    __shared__ float tile[32][33];
    int blk = blockIdx.x, tid = threadIdx.x;
    if (blk < 2048) {
        int j = blk;
        // columns [0,512) of WTj are never read (emb handled via embpart) — skip
        for (int k = 512 + tid; k < KX; k += 256) {
            float v = (k < 2560) ? Wih[(size_t)j * 2560 + k] : Whh[(size_t)j * 512 + (k - 2560)];
            WTj[(size_t)j * KX + k] = f2bf(v);
        }
        if (blk == 0) {
            for (int i = tid; i < 1664; i += 256) {
                if (i < 1600) cap_out[i] = (float)caps[i];
                else          len_out[i - 1600] = (float)(lens[i - 1600] - 1);
            }
        }
    } else if (blk < 3328) {
        int i = blk - 2048;
        int nb = (i % 80) * 32, kb = (i / 80) * 32;
        int tx = tid & 31, ty = tid >> 5;
        for (int s = 0; s < 32; s += 8) {
            int k = kb + ty + s, n = nb + tx;
            float v = (n < ATTD) ? Wd[(size_t)k * ATTD + n] : Wfb[(size_t)k * ENCD + (n - ATTD)];
            tile[ty + s][tx] = v;
        }
        __syncthreads();
        for (int s = 0; s < 32; s += 8)
            BpreT[(size_t)(nb + ty + s) * 512 + kb + tx] = f2bf(tile[tx][ty + s]);
    } else if (blk < 8384) {
        int i = blk - 3328;
        int nb = (i % 316) * 32, kb = (i / 316) * 32;
        int tx = tid & 31, ty = tid >> 5;
        for (int s = 0; s < 32; s += 8) {
            int k = kb + ty + s, n = nb + tx;
            float v = (n < NVOCAB) ? Wfc[(size_t)k * NVOCAB + n] : 0.f;
            tile[ty + s][tx] = v;
        }
        __syncthreads();
        for (int s = 0; s < 32; s += 8)
            WfcT[(size_t)(nb + ty + s) * 512 + kb + tx] = f2bf(tile[tx][ty + s]);
    } else if (blk < 9408) {
        int i = blk - 8384;
        int nb = (i % 16) * 32, kb = (i / 16) * 32;
        int tx = tid & 31, ty = tid >> 5;
        for (int s = 0; s < 32; s += 8) {
            int k = kb + ty + s, n = nb + tx;
            tile[ty + s][tx] = We[(size_t)k * ATTD + n];
        }
        __syncthreads();
        for (int s = 0; s < 32; s += 8)
            WeT[(size_t)(nb + ty + s) * ENCD + kb + tx] = f2bf(tile[tx][ty + s]);
    } else if (blk < 10176) {
        int i = blk - 9408;
        int r0 = (i % 24) * 64;
        int n0 = (i / 24) * 64;
        int w = tid >> 6, l = tid & 63;
        int m = l & 15, kg = l >> 4;
        int n = n0 + w * 16 + m;
        const float* Bp = Wih + (size_t)n * 2560 + kg * 8;
        int tok[4];
#pragma unroll
        for (int mf = 0; mf < 4; ++mf) {
            int row = r0 + m + mf * 16;
            tok[mf] = caps[(row & 63) * 25 + (row >> 6)];
        }
        f32x4 acc[4] = {};
        for (int k0 = 0; k0 < 512; k0 += 32) {
            float4 b0 = *(const float4*)(Bp + k0);
            float4 b1 = *(const float4*)(Bp + k0 + 4);
            bf16x8 bb;
            bb[0] = f2bf(b0.x); bb[1] = f2bf(b0.y); bb[2] = f2bf(b0.z); bb[3] = f2bf(b0.w);
            bb[4] = f2bf(b1.x); bb[5] = f2bf(b1.y); bb[6] = f2bf(b1.z); bb[7] = f2bf(b1.w);
#pragma unroll
            for (int mf = 0; mf < 4; ++mf) {
                const float* ap = emb + (size_t)tok[mf] * 512 + kg * 8 + k0;
                float4 f0 = *(const float4*)ap;
                float4 f1 = *(const float4*)(ap + 4);
                bf16x8 a;
                a[0] = f2bf(f0.x); a[1] = f2bf(f0.y); a[2] = f2bf(f0.z); a[3] = f2bf(f0.w);
                a[4] = f2bf(f1.x); a[5] = f2bf(f1.y); a[6] = f2bf(f1.z); a[7] = f2bf(f1.w);
                acc[mf] = __builtin_amdgcn_mfma_f32_16x16x32_bf16(a, bb, acc[mf], 0, 0, 0);
            }
        }
#pragma unroll
        for (int mf = 0; mf < 4; ++mf)
#pragma unroll
            for (int r = 0; r < 4; ++r)
                embpartb[(size_t)(r0 + mf * 16 + kg * 4 + r) * 2048 + n] = f2bf(acc[mf][r]);
    } else {
        int i = blk - 10176;
        for (int j = tid; j < 2048; j += 256) hcacc[(size_t)i * 2048 + j] = 0.f;
    }
}

// ---------------- enc fp32 -> bf16 ----------------
__global__ void k_encconv(const float* __restrict__ enc, ushort* __restrict__ encb) {
    size_t i = ((size_t)blockIdx.x * 256 + threadIdx.x) * 8;
    float4 f0 = *(const float4*)(enc + i);
    float4 f1 = *(const float4*)(enc + i + 4);
    union { bf16x8 v; ushort u[8]; } o;
    o.u[0] = f2bf(f0.x); o.u[1] = f2bf(f0.y); o.u[2] = f2bf(f0.z); o.u[3] = f2bf(f0.w);
    o.u[4] = f2bf(f1.x); o.u[5] = f2bf(f1.y); o.u[6] = f2bf(f1.z); o.u[7] = f2bf(f1.w);
    *(bf16x8*)(encb + i) = o.v;
}

// ---------------- mean over 196 positions ----------------
__global__ __launch_bounds__(256) void k_meanb(const ushort* __restrict__ encb,
                                               ushort* __restrict__ meanb) {
    int b = blockIdx.x, half = blockIdx.y;
    int e0 = half * 1024 + threadIdx.x * 4;
    const ushort* ep = encb + (size_t)b * NPIX * ENCD + e0;
    float s0 = 0.f, s1 = 0.f, s2 = 0.f, s3 = 0.f;
#pragma unroll 4
    for (int p = 0; p < NPIX; ++p) {
        ushort4 v = *(const ushort4*)(ep + (size_t)p * ENCD);
        s0 += bf2f(v.x); s1 += bf2f(v.y); s2 += bf2f(v.z); s3 += bf2f(v.w);
    }
    const float sc = 1.0f / NPIX;
    ushort4 o;
    o.x = f2bf(s0 * sc); o.y = f2bf(s1 * sc); o.z = f2bf(s2 * sc); o.w = f2bf(s3 * sc);
    *(ushort4*)(meanb + (size_t)b * ENCD + e0) = o;
}

// ---------------- h0/c0 init partials ----------------
__global__ __launch_bounds__(256) void k_initp(
        const ushort* __restrict__ meanb,
        const float* __restrict__ Wh, const float* __restrict__ Wc,
        float* __restrict__ hcacc) {
    __shared__ float mm[4][256];
    int bg = blockIdx.x * 4;
    int jy = blockIdx.y;
    int kz = blockIdx.z;
    int tid = threadIdx.x;
    for (int i = tid; i < 1024; i += 256) {
        int qq = i >> 8, k = i & 255;
        mm[qq][k] = bf2f(meanb[(size_t)(bg + qq) * ENCD + kz * 256 + k]);
    }
    __syncthreads();
    int j = jy * 256 + tid;
    const float* W; int col;
    if (j < 512) { W = Wh; col = j; } else { W = Wc; col = j - 512; }
    W += (size_t)(kz * 256) * 512 + col;
    float acc[4] = {};
    for (int k = 0; k < 256; ++k) {
        float w = W[(size_t)k * 512];
#pragma unroll
        for (int qq = 0; qq < 4; ++qq) acc[qq] += mm[qq][k] * w;
    }
#pragma unroll
    for (int qq = 0; qq < 4; ++qq)
        atomicAdd(hcacc + (size_t)(bg + qq) * 1024 + j, acc[qq]);
}

__global__ __launch_bounds__(256) void k_initfin(
        const float* __restrict__ hcacc, const float* __restrict__ bh,
        const float* __restrict__ bc, ushort* __restrict__ hbf,
        float* __restrict__ c) {
    int base = blockIdx.x * 2048;
    for (int i = threadIdx.x; i < 2048; i += 256) {
        int idx = base + i;
        int b = idx >> 10, n = idx & 1023;
        float v = hcacc[idx];
        if (n < 512) hbf[(size_t)b * 512 + n] = f2bf(v + bh[n]);
        else         c[(size_t)b * 512 + (n - 512)] = v + bc[n - 512];
    }
}

// ---------------- one-time: att1 = enc @ We + be ----------------
__global__ __launch_bounds__(256) void k_att1(
        const ushort* __restrict__ encb, const ushort* __restrict__ WeT,
        const float* __restrict__ be, ushort* __restrict__ att1b) {
    int w = threadIdx.x >> 6, l = threadIdx.x & 63;
    int wr = w >> 1, wc = w & 1;
    int m0 = blockIdx.x * 128 + wr * 64;
    int n0 = blockIdx.y * 128 + wc * 64;
    int ml = l & 15, kg = l >> 4;
    const ushort* aBase = encb + (size_t)(m0 + ml) * ENCD + kg * 8;
    const ushort* bBase = WeT + (size_t)(n0 + ml) * ENCD + kg * 8;
    f32x4 acc[4][4] = {};
    for (int k0 = 0; k0 < ENCD; k0 += 32) {
        bf16x8 bfr[4], afr[4];
#pragma unroll
        for (int nf = 0; nf < 4; ++nf)
            bfr[nf] = *(const bf16x8*)(bBase + (size_t)nf * 16 * ENCD + k0);
#pragma unroll
        for (int mf = 0; mf < 4; ++mf)
            afr[mf] = *(const bf16x8*)(aBase + (size_t)mf * 16 * ENCD + k0);
#pragma unroll
        for (int mf = 0; mf < 4; ++mf)
#pragma unroll
            for (int nf = 0; nf < 4; ++nf)
                acc[mf][nf] = __builtin_amdgcn_mfma_f32_16x16x32_bf16(afr[mf], bfr[nf], acc[mf][nf], 0, 0, 0);
    }
#pragma unroll
    for (int mf = 0; mf < 4; ++mf)
#pragma unroll
        for (int nf = 0; nf < 4; ++nf) {
            int col = n0 + nf * 16 + ml;
            float bias = be[col];
#pragma unroll
            for (int r = 0; r < 4; ++r) {
                int row = m0 + mf * 16 + kg * 4 + r;
                att1b[(size_t)row * ATTD + col] = f2bf(acc[mf][nf][r] + bias);
            }
        }
}

// ---------------- per-step K1: att2 + gate MFMA (40 blocks, K-split 2) ----------------
__global__ __launch_bounds__(512) void k_hsmall2(
        const ushort* __restrict__ hb_cur, const ushort* __restrict__ BpreT,
        const float* __restrict__ bd, const float* __restrict__ bfb,
        float* __restrict__ att2, ushort* __restrict__ gateb) {
    __shared__ float part[2][64][68];
    int blk = blockIdx.x;
    int tid = threadIdx.x;
    int w = tid >> 6, l = tid & 63;
    int wq = w & 3, kh = w >> 2;
    int m = l & 15, kg = l >> 4;
    int n = blk * 64 + wq * 16 + m;
    const ushort* B = BpreT + (size_t)n * 512 + kh * 256 + kg * 8;
    const ushort* A = hb_cur + (size_t)m * 512 + kh * 256 + kg * 8;
    f32x4 acc[4] = {};
#pragma unroll
    for (int k0 = 0; k0 < 256; k0 += 32) {
        bf16x8 bfr = *(const bf16x8*)(B + k0);
#pragma unroll
        for (int mf = 0; mf < 4; ++mf) {
            bf16x8 afr = *(const bf16x8*)(A + mf * 16 * 512 + k0);
            acc[mf] = __builtin_amdgcn_mfma_f32_16x16x32_bf16(afr, bfr, acc[mf], 0, 0, 0);
        }
    }
#pragma unroll
    for (int mf = 0; mf < 4; ++mf)
#pragma unroll
        for (int r = 0; r < 4; ++r)
            part[kh][mf * 16 + kg * 4 + r][wq * 16 + m] = acc[mf][r];
    __syncthreads();
    for (int idx = tid; idx < 4096; idx += 512) {
        int b = idx >> 6, nn = idx & 63;
        float v = part[0][b][nn] + part[1][b][nn];
        int ng = blk * 64 + nn;
        if (ng < 512) att2[(size_t)b * 512 + ng] = v + bd[ng];
        else {
            int e = ng - 512;
            gateb[(size_t)b * 2048 + e] = f2bf(1.f / (1.f + __expf(-(v + bfb[e]))));
        }
    }
}

// ---------------- per-step K2: scores+softmax (x4) + ctx quarter (XCD-swizzled) ----------------
__global__ __launch_bounds__(512) void k_scorectx(
        const ushort* __restrict__ att1b, const float* __restrict__ att2,
        const float* __restrict__ vatt, const float* __restrict__ bv,
        const ushort* __restrict__ gateb, const int* __restrict__ lens,
        const ushort* __restrict__ encb,
        ushort* __restrict__ ctxb, float* __restrict__ alpha_out, int t) {
    __shared__ float ev[200];
    __shared__ float cpart[4][512];
    __shared__ float inv_s;
    int bid = blockIdx.x;
    // XCD-friendly: the 4 q-blocks of a given b share bid%8 -> same XCD L2
    int b = ((bid & 7) << 3) | ((bid >> 3) & 7);
    int q = bid >> 6;
    int tid = threadIdx.x;
    int w = tid >> 6, l = tid & 63;
    {
        float a2r[8], vvr[8];
        const float* att2b = att2 + (size_t)b * ATTD;
#pragma unroll
        for (int i = 0; i < 8; ++i) {
            a2r[i] = att2b[l * 8 + i];
            vvr[i] = vatt[l * 8 + i];
        }
        float bv0 = bv[0];
        for (int pp = w; pp < NPIX; pp += 8) {
            bf16x8 f = *(const bf16x8*)(att1b + ((size_t)b * NPIX + pp) * ATTD + l * 8);
            float s = 0.f;
#pragma unroll
            for (int i = 0; i < 8; ++i)
                s += fmaxf(bf2f((ushort)f[i]) + a2r[i], 0.f) * vvr[i];
            for (int off = 32; off > 0; off >>= 1) s += __shfl_down(s, off);
            if (l == 0) ev[pp] = s + bv0;
        }
    }
    __syncthreads();
    if (w == 0) {
        float mx = -1e30f;
        for (int pp = l; pp < NPIX; pp += 64) mx = fmaxf(mx, ev[pp]);
        for (int off = 32; off > 0; off >>= 1) mx = fmaxf(mx, __shfl_down(mx, off));
        mx = __shfl(mx, 0);
        float s = 0.f;
        for (int pp = l; pp < NPIX; pp += 64) {
            float e_ = __expf(ev[pp] - mx);
            ev[pp] = e_;
            s += e_;
        }
        for (int off = 32; off > 0; off >>= 1) s += __shfl_down(s, off);
        if (l == 0) inv_s = 1.0f / s;
    }
    __syncthreads();
    float inv = inv_s;
    if (q == 0 && tid < NPIX) {
        bool active = t < (lens[b] - 1);
        alpha_out[((size_t)b * TSTEPS + t) * NPIX + tid] = active ? ev[tid] * inv : 0.f;
    }
    {
        int pg = tid >> 7, th = tid & 127;
        const ushort* ep = encb + (size_t)b * NPIX * ENCD + q * 512 + th * 4;
        float s0 = 0.f, s1 = 0.f, s2 = 0.f, s3 = 0.f;
        for (int pp = pg; pp < NPIX; pp += 4) {
            ushort4 v = *(const ushort4*)(ep + (size_t)pp * ENCD);
            float al = ev[pp];
            s0 += al * bf2f(v.x); s1 += al * bf2f(v.y);
            s2 += al * bf2f(v.z); s3 += al * bf2f(v.w);
        }
        cpart[pg][th * 4 + 0] = s0;
        cpart[pg][th * 4 + 1] = s1;
        cpart[pg][th * 4 + 2] = s2;
        cpart[pg][th * 4 + 3] = s3;
    }
    __syncthreads();
    if (tid < 128) {
        ushort4 g4 = *(const ushort4*)(gateb + (size_t)b * 2048 + q * 512 + tid * 4);
        ushort4 o;
        o.x = f2bf((cpart[0][tid * 4 + 0] + cpart[1][tid * 4 + 0] + cpart[2][tid * 4 + 0] + cpart[3][tid * 4 + 0]) * inv * bf2f(g4.x));
        o.y = f2bf((cpart[0][tid * 4 + 1] + cpart[1][tid * 4 + 1] + cpart[2][tid * 4 + 1] + cpart[3][tid * 4 + 1]) * inv * bf2f(g4.y));
        o.z = f2bf((cpart[0][tid * 4 + 2] + cpart[1][tid * 4 + 2] + cpart[2][tid * 4 + 2] + cpart[3][tid * 4 + 2]) * inv * bf2f(g4.z));
        o.w = f2bf((cpart[0][tid * 4 + 3] + cpart[1][tid * 4 + 3] + cpart[2][tid * 4 + 3] + cpart[3][tid * 4 + 3]) * inv * bf2f(g4.w));
        *(ushort4*)(ctxb + (size_t)b * 2048 + q * 512 + tid * 4) = o;
    }
}

// ---------------- per-step K3: gates GEMM (128 blocks, balanced 8-wave K-split) + LSTM ----------------
__global__ __launch_bounds__(512) void k_gates2(
        const ushort* __restrict__ ctxb, const ushort* __restrict__ hb_cur,
        const ushort* __restrict__ WTj, const ushort* __restrict__ embpartb,
        const float* __restrict__ bih, const float* __restrict__ bhh,
        const int* __restrict__ lens, float* __restrict__ c,
        ushort* __restrict__ hb_nxt, ushort* __restrict__ hAll, int t) {
    __shared__ float part[8][64][16];
    int g = blockIdx.x;
    int tid = threadIdx.x;
    int w = tid >> 6, l = tid & 63;
    int m = l & 15, kg = l >> 4;
    int jrow = (m >> 2) * 512 + g * 4 + (m & 3);
    const ushort* Brow = WTj + (size_t)jrow * KX;
    f32x4 acc[4] = {};
    // ctx part: wave w covers K-chunk [w*256, w*256+256) of the 2048 ctx dims
    {
        const ushort* B = Brow + 512 + w * 256 + kg * 8;
        const ushort* A = ctxb + (size_t)m * 2048 + w * 256 + kg * 8;
#pragma unroll
        for (int k0 = 0; k0 < 256; k0 += 32) {
            bf16x8 bfr = *(const bf16x8*)(B + k0);
#pragma unroll
            for (int mf = 0; mf < 4; ++mf) {
                bf16x8 afr = *(const bf16x8*)(A + (size_t)mf * 16 * 2048 + k0);
                acc[mf] = __builtin_amdgcn_mfma_f32_16x16x32_bf16(afr, bfr, acc[mf], 0, 0, 0);
            }
        }
    }
    // h part: balanced — wave w covers h-K [w*64, w*64+64)
    {
        const ushort* B = Brow + 2560 + w * 64 + kg * 8;
        const ushort* A = hb_cur + (size_t)m * 512 + w * 64 + kg * 8;
#pragma unroll
        for (int k0 = 0; k0 < 64; k0 += 32) {
            bf16x8 bfr = *(const bf16x8*)(B + k0);
#pragma unroll
            for (int mf = 0; mf < 4; ++mf) {
                bf16x8 afr = *(const bf16x8*)(A + (size_t)mf * 16 * 512 + k0);
                acc[mf] = __builtin_amdgcn_mfma_f32_16x16x32_bf16(afr, bfr, acc[mf], 0, 0, 0);
            }
        }
    }
#pragma unroll
    for (int mf = 0; mf < 4; ++mf)
#pragma unroll
        for (int r = 0; r < 4; ++r)
            part[w][mf * 16 + kg * 4 + r][m] = acc[mf][r];
    __syncthreads();
    if (tid < 256) {
        int bb = tid >> 2, j = tid & 3;
        int d = g * 4 + j;
        float gi = 0.f, gf = 0.f, gg = 0.f, go = 0.f;
#pragma unroll
        for (int w8 = 0; w8 < 8; ++w8) {
            gi += part[w8][bb][j];
            gf += part[w8][bb][4 + j];
            gg += part[w8][bb][8 + j];
            go += part[w8][bb][12 + j];
        }
        ushort hout = hb_cur[(size_t)bb * 512 + d];
        if (t < lens[bb] - 1) {
            const ushort* eb = embpartb + ((size_t)t * 64 + bb) * 2048;
            gi += bf2f(eb[d])        + bih[d]        + bhh[d];
            gf += bf2f(eb[512 + d])  + bih[512 + d]  + bhh[512 + d];
            gg += bf2f(eb[1024 + d]) + bih[1024 + d] + bhh[1024 + d];
            go += bf2f(eb[1536 + d]) + bih[1536 + d] + bhh[1536 + d];
            float cc = c[(size_t)bb * 512 + d];
            float si = 1.f / (1.f + __expf(-gi));
            float sf = 1.f / (1.f + __expf(-gf));
            float so = 1.f / (1.f + __expf(-go));
            float cn = sf * cc + si * tanhf(gg);
            float hn = so * tanhf(cn);
            c[(size_t)bb * 512 + d] = cn;
            hout = f2bf(hn);
        }
        hb_nxt[(size_t)bb * 512 + d] = hout;
        hAll[((size_t)t * 64 + bb) * 512 + d] = hout;
    }
}

// ---------------- post-loop: pred = hAll @ WfcT + bfc (masked) ----------------
__global__ __launch_bounds__(256) void k_predall(
        const ushort* __restrict__ hAll, const ushort* __restrict__ WfcT,
        const float* __restrict__ bfc, const int* __restrict__ lens,
        float* __restrict__ pred) {
    int w = threadIdx.x >> 6, l = threadIdx.x & 63;
    int wr = w >> 1, wc = w & 1;
    int m0 = blockIdx.x * 128 + wr * 64;
    int n0 = blockIdx.y * 128 + wc * 64;
    int ml = l & 15, kg = l >> 4;
    const ushort* aBase = hAll + (size_t)(m0 + ml) * 512 + kg * 8;
    const ushort* bBase = WfcT + (size_t)(n0 + ml) * 512 + kg * 8;
    f32x4 acc[4][4] = {};
#pragma unroll 2
    for (int k0 = 0; k0 < 512; k0 += 32) {
        bf16x8 bfr[4], afr[4];
#pragma unroll
        for (int nf = 0; nf < 4; ++nf)
            bfr[nf] = *(const bf16x8*)(bBase + (size_t)nf * 16 * 512 + k0);
#pragma unroll
        for (int mf = 0; mf < 4; ++mf)
            afr[mf] = *(const bf16x8*)(aBase + (size_t)mf * 16 * 512 + k0);
#pragma unroll
        for (int mf = 0; mf < 4; ++mf)
#pragma unroll
            for (int nf = 0; nf < 4; ++nf)
                acc[mf][nf] = __builtin_amdgcn_mfma_f32_16x16x32_bf16(afr[mf], bfr[nf], acc[mf][nf], 0, 0, 0);
    }
#pragma unroll
    for (int mf = 0; mf < 4; ++mf)
#pragma unroll
        for (int nf = 0; nf < 4; ++nf) {
            int col = n0 + nf * 16 + ml;
            if (col < NVOCAB) {
                float bias = bfc[col];
#pragma unroll
                for (int r = 0; r < 4; ++r) {
                    int row = m0 + mf * 16 + kg * 4 + r;
                    int t = row >> 6, b = row & 63;
                    bool act = t < (lens[b] - 1);
                    pred[((size_t)b * TSTEPS + t) * NVOCAB + col] = act ? acc[mf][nf][r] + bias : 0.f;
                }
            }
        }
}

extern "C" void kernel_launch(void* const* d_in, const int* in_sizes, int n_in,
                              void* d_out, int out_size, void* d_ws, size_t ws_size,
                              hipStream_t stream) {
    const float* enc  = (const float*)d_in[0];
    const int*   caps = (const int*)d_in[1];
    const int*   lens = (const int*)d_in[2];
    const float* emb  = (const float*)d_in[3];
    const float* We   = (const float*)d_in[4];
    const float* be   = (const float*)d_in[5];
    const float* Wd   = (const float*)d_in[6];
    const float* bd   = (const float*)d_in[7];
    const float* vatt = (const float*)d_in[8];
    const float* bv   = (const float*)d_in[9];
    const float* Wih  = (const float*)d_in[10];
    const float* bih  = (const float*)d_in[11];
    const float* Whh  = (const float*)d_in[12];
    const float* bhh  = (const float*)d_in[13];
    const float* Winh = (const float*)d_in[14];
    const float* binh = (const float*)d_in[15];
    const float* Winc = (const float*)d_in[16];
    const float* binc = (const float*)d_in[17];
    const float* Wfb  = (const float*)d_in[18];
    const float* bfb  = (const float*)d_in[19];
    const float* Wfc  = (const float*)d_in[20];
    const float* bfc  = (const float*)d_in[21];

    float* out       = (float*)d_out;
    float* pred_out  = out;
    float* cap_out   = out + 15360000;
    float* len_out   = out + 15361600;
    float* alpha_out = out + 15361664;

    char* p = (char*)d_ws;
    ushort* att1b    = (ushort*)p; p += (size_t)12544 * 512 * 2;
    ushort* WTj      = (ushort*)p; p += (size_t)2048 * KX * 2;
    ushort* WfcT     = (ushort*)p; p += (size_t)NPAD * 512 * 2;
    ushort* BpreT    = (ushort*)p; p += (size_t)2560 * 512 * 2;
    ushort* WeT      = (ushort*)p; p += (size_t)512 * 2048 * 2;
    ushort* embpartb = (ushort*)p; p += (size_t)1536 * 2048 * 2;
    ushort* hAll     = (ushort*)p; p += (size_t)1536 * 512 * 2;
    ushort* ctxb     = (ushort*)p; p += (size_t)64 * 2048 * 2;   // aliased: hcacc
    ushort* hb0      = (ushort*)p; p += (size_t)64 * 512 * 2;
    ushort* hb1      = (ushort*)p; p += (size_t)64 * 512 * 2;
    float* c         = (float*)p;  p += (size_t)64 * 512 * 4;
    ushort* meanb    = (ushort*)p; p += (size_t)64 * 2048 * 2;
    float* att2      = (float*)p;  p += (size_t)64 * 512 * 4;
    ushort* gateb    = (ushort*)p; p += (size_t)64 * 2048 * 2;
    ushort* encb     = (ushort*)p; p += (size_t)64 * NPIX * ENCD * 2;
    float* hcacc     = (float*)ctxb;

    k_prep<<<10208, 256, 0, stream>>>(Wih, Whh, Wd, Wfb, Wfc, We, emb, caps, lens,
                                      WTj, BpreT, WfcT, WeT, embpartb, hcacc,
                                      cap_out, len_out);
    k_encconv<<<12544, 256, 0, stream>>>(enc, encb);
    k_meanb<<<dim3(64, 2), 256, 0, stream>>>(encb, meanb);
    k_initp<<<dim3(16, 4, 8), 256, 0, stream>>>(meanb, Winh, Winc, hcacc);
    k_initfin<<<32, 256, 0, stream>>>(hcacc, binh, binc, hb0, c);
    k_att1<<<dim3(98, 4), 256, 0, stream>>>(encb, WeT, be, att1b);

    for (int t = 0; t < TSTEPS; ++t) {
        const ushort* hcur = (t & 1) ? hb1 : hb0;
        ushort* hnxt = (t & 1) ? hb0 : hb1;
        k_hsmall2<<<40, 512, 0, stream>>>(hcur, BpreT, bd, bfb, att2, gateb);
        k_scorectx<<<256, 512, 0, stream>>>(att1b, att2, vatt, bv, gateb, lens,
                                            encb, ctxb, alpha_out, t);
        k_gates2<<<128, 512, 0, stream>>>(ctxb, hcur, WTj, embpartb, bih, bhh,
                                          lens, c, hnxt, hAll, t);
    }
    k_predall<<<dim3(12, 79), 256, 0, stream>>>(hAll, WfcT, bfc, lens, pred_out);
}

// Round 12
// 1784.648 us; speedup vs baseline: 1.8310x; 1.0140x over previous
//
#include <hip/hip_runtime.h>
#include <hip/hip_bf16.h>

#define BATCH 64
#define NPIX 196
#define ENCD 2048
#define ATTD 512
#define DECD 512
#define EMBD 512
#define NVOCAB 10000
#define TSTEPS 24
#define KX 3072
#define NPAD 10112

typedef short bf16x8 __attribute__((ext_vector_type(8)));
typedef float f32x4 __attribute__((ext_vector_type(4)));

__device__ inline ushort f2bf(float f) {
    union { float f; unsigned u; } v; v.f = f;
    unsigned r = (v.u + 0x7fff + ((v.u >> 16) & 1)) >> 16;
    return (ushort)r;
}
__device__ inline float bf2f(ushort u) {
    union { unsigned u; float f; } v; v.u = ((unsigned)u) << 16;
    return v.f;
}

// ================= fused one-time prep (64x64 transpose tiles) =================
// ranges: [0,2048) WTj copy (+meta blk0); [2048,2368) BpreT; [2368,3632) WfcT;
// [3632,3888) WeT; [3888,4656) embpart; [4656,4688) hcacc zero.
__global__ __launch_bounds__(256) void k_prep(
        const float* __restrict__ Wih, const float* __restrict__ Whh,
        const float* __restrict__ Wd, const float* __restrict__ Wfb,
        const float* __restrict__ Wfc, const float* __restrict__ We,
        const float* __restrict__ emb, const int* __restrict__ caps,
        const int* __restrict__ lens,
        ushort* __restrict__ WTj, ushort* __restrict__ BpreT,
        ushort* __restrict__ WfcT, ushort* __restrict__ WeT,
        ushort* __restrict__ embpartb, float* __restrict__ hcacc,
        float* __restrict__ cap_out, float* __restrict__ len_out) {
    __shared__ float tile[64][65];
    int blk = blockIdx.x, tid = threadIdx.x;
    int tx = tid & 63, ty = tid >> 6;   // 64 x 4
    if (blk < 2048) {
        int j = blk;
        // columns [0,512) of WTj are never read (emb handled via embpart) — skip
        for (int k = 512 + tid; k < KX; k += 256) {
            float v = (k < 2560) ? Wih[(size_t)j * 2560 + k] : Whh[(size_t)j * 512 + (k - 2560)];
            WTj[(size_t)j * KX + k] = f2bf(v);
        }
        if (blk == 0) {
            for (int i = tid; i < 1664; i += 256) {
                if (i < 1600) cap_out[i] = (float)caps[i];
                else          len_out[i - 1600] = (float)(lens[i - 1600] - 1);
            }
        }
    } else if (blk < 2368) {
        int i = blk - 2048;
        int nb = (i % 40) * 64, kb = (i / 40) * 64;
        for (int s = 0; s < 64; s += 4) {
            int k = kb + ty + s, n = nb + tx;
            float v = (n < ATTD) ? Wd[(size_t)k * ATTD + n] : Wfb[(size_t)k * ENCD + (n - ATTD)];
            tile[ty + s][tx] = v;
        }
        __syncthreads();
        for (int s = 0; s < 64; s += 4)
            BpreT[(size_t)(nb + ty + s) * 512 + kb + tx] = f2bf(tile[tx][ty + s]);
    } else if (blk < 3632) {
        int i = blk - 2368;
        int nb = (i % 158) * 64, kb = (i / 158) * 64;
        for (int s = 0; s < 64; s += 4) {
            int k = kb + ty + s, n = nb + tx;
            float v = (n < NVOCAB) ? Wfc[(size_t)k * NVOCAB + n] : 0.f;
            tile[ty + s][tx] = v;
        }
        __syncthreads();
        for (int s = 0; s < 64; s += 4)
            WfcT[(size_t)(nb + ty + s) * 512 + kb + tx] = f2bf(tile[tx][ty + s]);
    } else if (blk < 3888) {
        int i = blk - 3632;
        int nb = (i % 8) * 64, kb = (i / 8) * 64;
        for (int s = 0; s < 64; s += 4) {
            int k = kb + ty + s, n = nb + tx;
            tile[ty + s][tx] = We[(size_t)k * ATTD + n];
        }
        __syncthreads();
        for (int s = 0; s < 64; s += 4)
            WeT[(size_t)(nb + ty + s) * ENCD + kb + tx] = f2bf(tile[tx][ty + s]);
    } else if (blk < 4656) {
        int i = blk - 3888;
        int r0 = (i % 24) * 64;
        int n0 = (i / 24) * 64;
        int w = tid >> 6, l = tid & 63;
        int m = l & 15, kg = l >> 4;
        int n = n0 + w * 16 + m;
        const float* Bp = Wih + (size_t)n * 2560 + kg * 8;
        int tok[4];
#pragma unroll
        for (int mf = 0; mf < 4; ++mf) {
            int row = r0 + m + mf * 16;
            tok[mf] = caps[(row & 63) * 25 + (row >> 6)];
        }
        f32x4 acc[4] = {};
        for (int k0 = 0; k0 < 512; k0 += 32) {
            float4 b0 = *(const float4*)(Bp + k0);
            float4 b1 = *(const float4*)(Bp + k0 + 4);
            bf16x8 bb;
            bb[0] = f2bf(b0.x); bb[1] = f2bf(b0.y); bb[2] = f2bf(b0.z); bb[3] = f2bf(b0.w);
            bb[4] = f2bf(b1.x); bb[5] = f2bf(b1.y); bb[6] = f2bf(b1.z); bb[7] = f2bf(b1.w);
#pragma unroll
            for (int mf = 0; mf < 4; ++mf) {
                const float* ap = emb + (size_t)tok[mf] * 512 + kg * 8 + k0;
                float4 f0 = *(const float4*)ap;
                float4 f1 = *(const float4*)(ap + 4);
                bf16x8 a;
                a[0] = f2bf(f0.x); a[1] = f2bf(f0.y); a[2] = f2bf(f0.z); a[3] = f2bf(f0.w);
                a[4] = f2bf(f1.x); a[5] = f2bf(f1.y); a[6] = f2bf(f1.z); a[7] = f2bf(f1.w);
                acc[mf] = __builtin_amdgcn_mfma_f32_16x16x32_bf16(a, bb, acc[mf], 0, 0, 0);
            }
        }
#pragma unroll
        for (int mf = 0; mf < 4; ++mf)
#pragma unroll
            for (int r = 0; r < 4; ++r)
                embpartb[(size_t)(r0 + mf * 16 + kg * 4 + r) * 2048 + n] = f2bf(acc[mf][r]);
    } else {
        int i = blk - 4656;
        for (int j = tid; j < 2048; j += 256) hcacc[(size_t)i * 2048 + j] = 0.f;
    }
}

// ---------------- enc fp32 -> bf16 ----------------
__global__ void k_encconv(const float* __restrict__ enc, ushort* __restrict__ encb) {
    size_t i = ((size_t)blockIdx.x * 256 + threadIdx.x) * 8;
    float4 f0 = *(const float4*)(enc + i);
    float4 f1 = *(const float4*)(enc + i + 4);
    union { bf16x8 v; ushort u[8]; } o;
    o.u[0] = f2bf(f0.x); o.u[1] = f2bf(f0.y); o.u[2] = f2bf(f0.z); o.u[3] = f2bf(f0.w);
    o.u[4] = f2bf(f1.x); o.u[5] = f2bf(f1.y); o.u[6] = f2bf(f1.z); o.u[7] = f2bf(f1.w);
    *(bf16x8*)(encb + i) = o.v;
}

// ---------------- mean over 196 positions ----------------
__global__ __launch_bounds__(256) void k_meanb(const ushort* __restrict__ encb,
                                               ushort* __restrict__ meanb) {
    int b = blockIdx.x, half = blockIdx.y;
    int e0 = half * 1024 + threadIdx.x * 4;
    const ushort* ep = encb + (size_t)b * NPIX * ENCD + e0;
    float s0 = 0.f, s1 = 0.f, s2 = 0.f, s3 = 0.f;
#pragma unroll 4
    for (int p = 0; p < NPIX; ++p) {
        ushort4 v = *(const ushort4*)(ep + (size_t)p * ENCD);
        s0 += bf2f(v.x); s1 += bf2f(v.y); s2 += bf2f(v.z); s3 += bf2f(v.w);
    }
    const float sc = 1.0f / NPIX;
    ushort4 o;
    o.x = f2bf(s0 * sc); o.y = f2bf(s1 * sc); o.z = f2bf(s2 * sc); o.w = f2bf(s3 * sc);
    *(ushort4*)(meanb + (size_t)b * ENCD + e0) = o;
}

// ---------------- h0/c0 init partials ----------------
__global__ __launch_bounds__(256) void k_initp(
        const ushort* __restrict__ meanb,
        const float* __restrict__ Wh, const float* __restrict__ Wc,
        float* __restrict__ hcacc) {
    __shared__ float mm[4][256];
    int bg = blockIdx.x * 4;
    int jy = blockIdx.y;
    int kz = blockIdx.z;
    int tid = threadIdx.x;
    for (int i = tid; i < 1024; i += 256) {
        int qq = i >> 8, k = i & 255;
        mm[qq][k] = bf2f(meanb[(size_t)(bg + qq) * ENCD + kz * 256 + k]);
    }
    __syncthreads();
    int j = jy * 256 + tid;
    const float* W; int col;
    if (j < 512) { W = Wh; col = j; } else { W = Wc; col = j - 512; }
    W += (size_t)(kz * 256) * 512 + col;
    float acc[4] = {};
    for (int k = 0; k < 256; ++k) {
        float w = W[(size_t)k * 512];
#pragma unroll
        for (int qq = 0; qq < 4; ++qq) acc[qq] += mm[qq][k] * w;
    }
#pragma unroll
    for (int qq = 0; qq < 4; ++qq)
        atomicAdd(hcacc + (size_t)(bg + qq) * 1024 + j, acc[qq]);
}

__global__ __launch_bounds__(256) void k_initfin(
        const float* __restrict__ hcacc, const float* __restrict__ bh,
        const float* __restrict__ bc, ushort* __restrict__ hbf,
        float* __restrict__ c) {
    int base = blockIdx.x * 2048;
    for (int i = threadIdx.x; i < 2048; i += 256) {
        int idx = base + i;
        int b = idx >> 10, n = idx & 1023;
        float v = hcacc[idx];
        if (n < 512) hbf[(size_t)b * 512 + n] = f2bf(v + bh[n]);
        else         c[(size_t)b * 512 + (n - 512)] = v + bc[n - 512];
    }
}

// ---------------- one-time: att1 = enc @ We + be (128x128 tile + XCD swizzle) ----------------
__global__ __launch_bounds__(256) void k_att1(
        const ushort* __restrict__ encb, const ushort* __restrict__ WeT,
        const float* __restrict__ be, ushort* __restrict__ att1b) {
    int bid = blockIdx.x;                       // 392 blocks
    int L = (bid & 7) * 49 + (bid >> 3);        // bijective; 4 n-tiles of one m share bid&7 (XCD)
    int mt = L >> 2, nt = L & 3;
    int w = threadIdx.x >> 6, l = threadIdx.x & 63;
    int wr = w >> 1, wc = w & 1;
    int m0 = mt * 128 + wr * 64;
    int n0 = nt * 128 + wc * 64;
    int ml = l & 15, kg = l >> 4;
    const ushort* aBase = encb + (size_t)(m0 + ml) * ENCD + kg * 8;
    const ushort* bBase = WeT + (size_t)(n0 + ml) * ENCD + kg * 8;
    f32x4 acc[4][4] = {};
    for (int k0 = 0; k0 < ENCD; k0 += 32) {
        bf16x8 bfr[4], afr[4];
#pragma unroll
        for (int nf = 0; nf < 4; ++nf)
            bfr[nf] = *(const bf16x8*)(bBase + (size_t)nf * 16 * ENCD + k0);
#pragma unroll
        for (int mf = 0; mf < 4; ++mf)
            afr[mf] = *(const bf16x8*)(aBase + (size_t)mf * 16 * ENCD + k0);
#pragma unroll
        for (int mf = 0; mf < 4; ++mf)
#pragma unroll
            for (int nf = 0; nf < 4; ++nf)
                acc[mf][nf] = __builtin_amdgcn_mfma_f32_16x16x32_bf16(afr[mf], bfr[nf], acc[mf][nf], 0, 0, 0);
    }
#pragma unroll
    for (int mf = 0; mf < 4; ++mf)
#pragma unroll
        for (int nf = 0; nf < 4; ++nf) {
            int col = n0 + nf * 16 + ml;
            float bias = be[col];
#pragma unroll
            for (int r = 0; r < 4; ++r) {
                int row = m0 + mf * 16 + kg * 4 + r;
                att1b[(size_t)row * ATTD + col] = f2bf(acc[mf][nf][r] + bias);
            }
        }
}

// ---------------- per-step K1: att2 + gate MFMA (40 blocks, K-split 2) ----------------
__global__ __launch_bounds__(512) void k_hsmall2(
        const ushort* __restrict__ hb_cur, const ushort* __restrict__ BpreT,
        const float* __restrict__ bd, const float* __restrict__ bfb,
        float* __restrict__ att2, ushort* __restrict__ gateb) {
    __shared__ float part[2][64][68];
    int blk = blockIdx.x;
    int tid = threadIdx.x;
    int w = tid >> 6, l = tid & 63;
    int wq = w & 3, kh = w >> 2;
    int m = l & 15, kg = l >> 4;
    int n = blk * 64 + wq * 16 + m;
    const ushort* B = BpreT + (size_t)n * 512 + kh * 256 + kg * 8;
    const ushort* A = hb_cur + (size_t)m * 512 + kh * 256 + kg * 8;
    f32x4 acc[4] = {};
#pragma unroll
    for (int k0 = 0; k0 < 256; k0 += 32) {
        bf16x8 bfr = *(const bf16x8*)(B + k0);
#pragma unroll
        for (int mf = 0; mf < 4; ++mf) {
            bf16x8 afr = *(const bf16x8*)(A + mf * 16 * 512 + k0);
            acc[mf] = __builtin_amdgcn_mfma_f32_16x16x32_bf16(afr, bfr, acc[mf], 0, 0, 0);
        }
    }
#pragma unroll
    for (int mf = 0; mf < 4; ++mf)
#pragma unroll
        for (int r = 0; r < 4; ++r)
            part[kh][mf * 16 + kg * 4 + r][wq * 16 + m] = acc[mf][r];
    __syncthreads();
    for (int idx = tid; idx < 4096; idx += 512) {
        int b = idx >> 6, nn = idx & 63;
        float v = part[0][b][nn] + part[1][b][nn];
        int ng = blk * 64 + nn;
        if (ng < 512) att2[(size_t)b * 512 + ng] = v + bd[ng];
        else {
            int e = ng - 512;
            gateb[(size_t)b * 2048 + e] = f2bf(1.f / (1.f + __expf(-(v + bfb[e]))));
        }
    }
}

// ---------------- per-step K2: scores+softmax (x4) + ctx quarter (XCD swizzle, early-exit) ----------------
__global__ __launch_bounds__(512) void k_scorectx(
        const ushort* __restrict__ att1b, const float* __restrict__ att2,
        const float* __restrict__ vatt, const float* __restrict__ bv,
        const ushort* __restrict__ gateb, const int* __restrict__ lens,
        const ushort* __restrict__ encb,
        ushort* __restrict__ ctxb, float* __restrict__ alpha_out, int t) {
    __shared__ float ev[200];
    __shared__ float cpart[4][512];
    __shared__ float inv_s;
    int bid = blockIdx.x;
    // XCD-friendly: the 4 q-blocks of a given b share bid%8 -> same XCD L2
    int b = ((bid & 7) << 3) | ((bid >> 3) & 7);
    int q = bid >> 6;
    int tid = threadIdx.x;
    int w = tid >> 6, l = tid & 63;
    // inactive row: only alpha zeros needed; ctxb row goes stale (finite; gates2 never
    // stores for inactive rows; t=0 is active for all b so no poison survives)
    if (t >= lens[b] - 1) {
        if (q == 0 && tid < NPIX)
            alpha_out[((size_t)b * TSTEPS + t) * NPIX + tid] = 0.f;
        return;
    }
    {
        float a2r[8], vvr[8];
        const float* att2b = att2 + (size_t)b * ATTD;
#pragma unroll
        for (int i = 0; i < 8; ++i) {
            a2r[i] = att2b[l * 8 + i];
            vvr[i] = vatt[l * 8 + i];
        }
        float bv0 = bv[0];
        for (int pp = w; pp < NPIX; pp += 8) {
            bf16x8 f = *(const bf16x8*)(att1b + ((size_t)b * NPIX + pp) * ATTD + l * 8);
            float s = 0.f;
#pragma unroll
            for (int i = 0; i < 8; ++i)
                s += fmaxf(bf2f((ushort)f[i]) + a2r[i], 0.f) * vvr[i];
            for (int off = 32; off > 0; off >>= 1) s += __shfl_down(s, off);
            if (l == 0) ev[pp] = s + bv0;
        }
    }
    __syncthreads();
    if (w == 0) {
        float mx = -1e30f;
        for (int pp = l; pp < NPIX; pp += 64) mx = fmaxf(mx, ev[pp]);
        for (int off = 32; off > 0; off >>= 1) mx = fmaxf(mx, __shfl_down(mx, off));
        mx = __shfl(mx, 0);
        float s = 0.f;
        for (int pp = l; pp < NPIX; pp += 64) {
            float e_ = __expf(ev[pp] - mx);
            ev[pp] = e_;
            s += e_;
        }
        for (int off = 32; off > 0; off >>= 1) s += __shfl_down(s, off);
        if (l == 0) inv_s = 1.0f / s;
    }
    __syncthreads();
    float inv = inv_s;
    if (q == 0 && tid < NPIX)
        alpha_out[((size_t)b * TSTEPS + t) * NPIX + tid] = ev[tid] * inv;
    {
        int pg = tid >> 7, th = tid & 127;
        const ushort* ep = encb + (size_t)b * NPIX * ENCD + q * 512 + th * 4;
        float s0 = 0.f, s1 = 0.f, s2 = 0.f, s3 = 0.f;
        for (int pp = pg; pp < NPIX; pp += 4) {
            ushort4 v = *(const ushort4*)(ep + (size_t)pp * ENCD);
            float al = ev[pp];
            s0 += al * bf2f(v.x); s1 += al * bf2f(v.y);
            s2 += al * bf2f(v.z); s3 += al * bf2f(v.w);
        }
        cpart[pg][th * 4 + 0] = s0;
        cpart[pg][th * 4 + 1] = s1;
        cpart[pg][th * 4 + 2] = s2;
        cpart[pg][th * 4 + 3] = s3;
    }
    __syncthreads();
    if (tid < 128) {
        ushort4 g4 = *(const ushort4*)(gateb + (size_t)b * 2048 + q * 512 + tid * 4);
        ushort4 o;
        o.x = f2bf((cpart[0][tid * 4 + 0] + cpart[1][tid * 4 + 0] + cpart[2][tid * 4 + 0] + cpart[3][tid * 4 + 0]) * inv * bf2f(g4.x));
        o.y = f2bf((cpart[0][tid * 4 + 1] + cpart[1][tid * 4 + 1] + cpart[2][tid * 4 + 1] + cpart[3][tid * 4 + 1]) * inv * bf2f(g4.y));
        o.z = f2bf((cpart[0][tid * 4 + 2] + cpart[1][tid * 4 + 2] + cpart[2][tid * 4 + 2] + cpart[3][tid * 4 + 2]) * inv * bf2f(g4.z));
        o.w = f2bf((cpart[0][tid * 4 + 3] + cpart[1][tid * 4 + 3] + cpart[2][tid * 4 + 3] + cpart[3][tid * 4 + 3]) * inv * bf2f(g4.w));
        *(ushort4*)(ctxb + (size_t)b * 2048 + q * 512 + tid * 4) = o;
    }
}

// ---------------- per-step K3: gates GEMM (128 blocks, balanced 8-wave K-split) + LSTM ----------------
__global__ __launch_bounds__(512) void k_gates2(
        const ushort* __restrict__ ctxb, const ushort* __restrict__ hb_cur,
        const ushort* __restrict__ WTj, const ushort* __restrict__ embpartb,
        const float* __restrict__ bih, const float* __restrict__ bhh,
        const int* __restrict__ lens, float* __restrict__ c,
        ushort* __restrict__ hb_nxt, ushort* __restrict__ hAll, int t) {
    __shared__ float part[8][64][16];
    int g = blockIdx.x;
    int tid = threadIdx.x;
    int w = tid >> 6, l = tid & 63;
    int m = l & 15, kg = l >> 4;
    int jrow = (m >> 2) * 512 + g * 4 + (m & 3);
    const ushort* Brow = WTj + (size_t)jrow * KX;
    f32x4 acc[4] = {};
    // ctx part: wave w covers K-chunk [w*256, w*256+256)
    {
        const ushort* B = Brow + 512 + w * 256 + kg * 8;
        const ushort* A = ctxb + (size_t)m * 2048 + w * 256 + kg * 8;
#pragma unroll
        for (int k0 = 0; k0 < 256; k0 += 32) {
            bf16x8 bfr = *(const bf16x8*)(B + k0);
#pragma unroll
            for (int mf = 0; mf < 4; ++mf) {
                bf16x8 afr = *(const bf16x8*)(A + (size_t)mf * 16 * 2048 + k0);
                acc[mf] = __builtin_amdgcn_mfma_f32_16x16x32_bf16(afr, bfr, acc[mf], 0, 0, 0);
            }
        }
    }
    // h part: wave w covers h-K [w*64, w*64+64)
    {
        const ushort* B = Brow + 2560 + w * 64 + kg * 8;
        const ushort* A = hb_cur + (size_t)m * 512 + w * 64 + kg * 8;
#pragma unroll
        for (int k0 = 0; k0 < 64; k0 += 32) {
            bf16x8 bfr = *(const bf16x8*)(B + k0);
#pragma unroll
            for (int mf = 0; mf < 4; ++mf) {
                bf16x8 afr = *(const bf16x8*)(A + (size_t)mf * 16 * 512 + k0);
                acc[mf] = __builtin_amdgcn_mfma_f32_16x16x32_bf16(afr, bfr, acc[mf], 0, 0, 0);
            }
        }
    }
#pragma unroll
    for (int mf = 0; mf < 4; ++mf)
#pragma unroll
        for (int r = 0; r < 4; ++r)
            part[w][mf * 16 + kg * 4 + r][m] = acc[mf][r];
    __syncthreads();
    if (tid < 256) {
        int bb = tid >> 2, j = tid & 3;
        int d = g * 4 + j;
        float gi = 0.f, gf = 0.f, gg = 0.f, go = 0.f;
#pragma unroll
        for (int w8 = 0; w8 < 8; ++w8) {
            gi += part[w8][bb][j];
            gf += part[w8][bb][4 + j];
            gg += part[w8][bb][8 + j];
            go += part[w8][bb][12 + j];
        }
        ushort hout = hb_cur[(size_t)bb * 512 + d];
        if (t < lens[bb] - 1) {
            const ushort* eb = embpartb + ((size_t)t * 64 + bb) * 2048;
            gi += bf2f(eb[d])        + bih[d]        + bhh[d];
            gf += bf2f(eb[512 + d])  + bih[512 + d]  + bhh[512 + d];
            gg += bf2f(eb[1024 + d]) + bih[1024 + d] + bhh[1024 + d];
            go += bf2f(eb[1536 + d]) + bih[1536 + d] + bhh[1536 + d];
            float cc = c[(size_t)bb * 512 + d];
            float si = 1.f / (1.f + __expf(-gi));
            float sf = 1.f / (1.f + __expf(-gf));
            float so = 1.f / (1.f + __expf(-go));
            float cn = sf * cc + si * tanhf(gg);
            float hn = so * tanhf(cn);
            c[(size_t)bb * 512 + d] = cn;
            hout = f2bf(hn);
        }
        hb_nxt[(size_t)bb * 512 + d] = hout;
        hAll[((size_t)t * 64 + bb) * 512 + d] = hout;
    }
}

// ---------------- post-loop: pred = hAll @ WfcT + bfc (masked) ----------------
__global__ __launch_bounds__(256) void k_predall(
        const ushort* __restrict__ hAll, const ushort* __restrict__ WfcT,
        const float* __restrict__ bfc, const int* __restrict__ lens,
        float* __restrict__ pred) {
    int w = threadIdx.x >> 6, l = threadIdx.x & 63;
    int wr = w >> 1, wc = w & 1;
    int m0 = blockIdx.x * 128 + wr * 64;
    int n0 = blockIdx.y * 128 + wc * 64;
    int ml = l & 15, kg = l >> 4;
    const ushort* aBase = hAll + (size_t)(m0 + ml) * 512 + kg * 8;
    const ushort* bBase = WfcT + (size_t)(n0 + ml) * 512 + kg * 8;
    f32x4 acc[4][4] = {};
#pragma unroll 2
    for (int k0 = 0; k0 < 512; k0 += 32) {
        bf16x8 bfr[4], afr[4];
#pragma unroll
        for (int nf = 0; nf < 4; ++nf)
            bfr[nf] = *(const bf16x8*)(bBase + (size_t)nf * 16 * 512 + k0);
#pragma unroll
        for (int mf = 0; mf < 4; ++mf)
            afr[mf] = *(const bf16x8*)(aBase + (size_t)mf * 16 * 512 + k0);
#pragma unroll
        for (int mf = 0; mf < 4; ++mf)
#pragma unroll
            for (int nf = 0; nf < 4; ++nf)
                acc[mf][nf] = __builtin_amdgcn_mfma_f32_16x16x32_bf16(afr[mf], bfr[nf], acc[mf][nf], 0, 0, 0);
    }
#pragma unroll
    for (int mf = 0; mf < 4; ++mf)
#pragma unroll
        for (int nf = 0; nf < 4; ++nf) {
            int col = n0 + nf * 16 + ml;
            if (col < NVOCAB) {
                float bias = bfc[col];
#pragma unroll
                for (int r = 0; r < 4; ++r) {
                    int row = m0 + mf * 16 + kg * 4 + r;
                    int t = row >> 6, b = row & 63;
                    bool act = t < (lens[b] - 1);
                    pred[((size_t)b * TSTEPS + t) * NVOCAB + col] = act ? acc[mf][nf][r] + bias : 0.f;
                }
            }
        }
}

extern "C" void kernel_launch(void* const* d_in, const int* in_sizes, int n_in,
                              void* d_out, int out_size, void* d_ws, size_t ws_size,
                              hipStream_t stream) {
    const float* enc  = (const float*)d_in[0];
    const int*   caps = (const int*)d_in[1];
    const int*   lens = (const int*)d_in[2];
    const float* emb  = (const float*)d_in[3];
    const float* We   = (const float*)d_in[4];
    const float* be   = (const float*)d_in[5];
    const float* Wd   = (const float*)d_in[6];
    const float* bd   = (const float*)d_in[7];
    const float* vatt = (const float*)d_in[8];
    const float* bv   = (const float*)d_in[9];
    const float* Wih  = (const float*)d_in[10];
    const float* bih  = (const float*)d_in[11];
    const float* Whh  = (const float*)d_in[12];
    const float* bhh  = (const float*)d_in[13];
    const float* Winh = (const float*)d_in[14];
    const float* binh = (const float*)d_in[15];
    const float* Winc = (const float*)d_in[16];
    const float* binc = (const float*)d_in[17];
    const float* Wfb  = (const float*)d_in[18];
    const float* bfb  = (const float*)d_in[19];
    const float* Wfc  = (const float*)d_in[20];
    const float* bfc  = (const float*)d_in[21];

    float* out       = (float*)d_out;
    float* pred_out  = out;
    float* cap_out   = out + 15360000;
    float* len_out   = out + 15361600;
    float* alpha_out = out + 15361664;

    char* p = (char*)d_ws;
    ushort* att1b    = (ushort*)p; p += (size_t)12544 * 512 * 2;
    ushort* WTj      = (ushort*)p; p += (size_t)2048 * KX * 2;
    ushort* WfcT     = (ushort*)p; p += (size_t)NPAD * 512 * 2;
    ushort* BpreT    = (ushort*)p; p += (size_t)2560 * 512 * 2;
    ushort* WeT      = (ushort*)p; p += (size_t)512 * 2048 * 2;
    ushort* embpartb = (ushort*)p; p += (size_t)1536 * 2048 * 2;
    ushort* hAll     = (ushort*)p; p += (size_t)1536 * 512 * 2;
    ushort* ctxb     = (ushort*)p; p += (size_t)64 * 2048 * 2;   // aliased: hcacc
    ushort* hb0      = (ushort*)p; p += (size_t)64 * 512 * 2;
    ushort* hb1      = (ushort*)p; p += (size_t)64 * 512 * 2;
    float* c         = (float*)p;  p += (size_t)64 * 512 * 4;
    ushort* meanb    = (ushort*)p; p += (size_t)64 * 2048 * 2;
    float* att2      = (float*)p;  p += (size_t)64 * 512 * 4;
    ushort* gateb    = (ushort*)p; p += (size_t)64 * 2048 * 2;
    ushort* encb     = (ushort*)p; p += (size_t)64 * NPIX * ENCD * 2;
    float* hcacc     = (float*)ctxb;

    k_prep<<<4688, 256, 0, stream>>>(Wih, Whh, Wd, Wfb, Wfc, We, emb, caps, lens,
                                     WTj, BpreT, WfcT, WeT, embpartb, hcacc,
                                     cap_out, len_out);
    k_encconv<<<12544, 256, 0, stream>>>(enc, encb);
    k_meanb<<<dim3(64, 2), 256, 0, stream>>>(encb, meanb);
    k_initp<<<dim3(16, 4, 8), 256, 0, stream>>>(meanb, Winh, Winc, hcacc);
    k_initfin<<<32, 256, 0, stream>>>(hcacc, binh, binc, hb0, c);
    k_att1<<<392, 256, 0, stream>>>(encb, WeT, be, att1b);

    for (int t = 0; t < TSTEPS; ++t) {
        const ushort* hcur = (t & 1) ? hb1 : hb0;
        ushort* hnxt = (t & 1) ? hb0 : hb1;
        k_hsmall2<<<40, 512, 0, stream>>>(hcur, BpreT, bd, bfb, att2, gateb);
        k_scorectx<<<256, 512, 0, stream>>>(att1b, att2, vatt, bv, gateb, lens,
                                            encb, ctxb, alpha_out, t);
        k_gates2<<<128, 512, 0, stream>>>(ctxb, hcur, WTj, embpartb, bih, bhh,
                                          lens, c, hnxt, hAll, t);
    }
    k_predall<<<dim3(12, 79), 256, 0, stream>>>(hAll, WfcT, bfc, lens, pred_out);
}

// Round 13
// 1778.156 us; speedup vs baseline: 1.8377x; 1.0037x over previous
//
#include <hip/hip_runtime.h>
#include <hip/hip_bf16.h>

#define BATCH 64
#define NPIX 196
#define ENCD 2048
#define ATTD 512
#define DECD 512
#define EMBD 512
#define NVOCAB 10000
#define TSTEPS 24
#define KX 3072
#define NPAD 10112

typedef short bf16x8 __attribute__((ext_vector_type(8)));
typedef float f32x4 __attribute__((ext_vector_type(4)));

__device__ inline ushort f2bf(float f) {
    union { float f; unsigned u; } v; v.f = f;
    unsigned r = (v.u + 0x7fff + ((v.u >> 16) & 1)) >> 16;
    return (ushort)r;
}
__device__ inline float bf2f(ushort u) {
    union { unsigned u; float f; } v; v.u = ((unsigned)u) << 16;
    return v.f;
}

// ================= fused one-time prep (64x64 transpose tiles, float4 reads) =================
// ranges: [0,2048) WTj copy (+meta blk0); [2048,2368) BpreT; [2368,3632) WfcT;
// [3632,3888) WeT; [3888,4656) embpart; [4656,4688) hcacc zero.
__global__ __launch_bounds__(256) void k_prep(
        const float* __restrict__ Wih, const float* __restrict__ Whh,
        const float* __restrict__ Wd, const float* __restrict__ Wfb,
        const float* __restrict__ Wfc, const float* __restrict__ We,
        const float* __restrict__ emb, const int* __restrict__ caps,
        const int* __restrict__ lens,
        ushort* __restrict__ WTj, ushort* __restrict__ BpreT,
        ushort* __restrict__ WfcT, ushort* __restrict__ WeT,
        ushort* __restrict__ embpartb, float* __restrict__ hcacc,
        float* __restrict__ cap_out, float* __restrict__ len_out) {
    __shared__ float tile[64][65];
    int blk = blockIdx.x, tid = threadIdx.x;
    int tx = tid & 63, ty = tid >> 6;   // 64 x 4 (write layout)
    int fx = tid & 15, fy = tid >> 4;   // 16 x 16 (float4 read layout)
    if (blk < 2048) {
        int j = blk;
        // columns [0,512) of WTj are never read (emb handled via embpart) — skip
        for (int k = 512 + tid; k < KX; k += 256) {
            float v = (k < 2560) ? Wih[(size_t)j * 2560 + k] : Whh[(size_t)j * 512 + (k - 2560)];
            WTj[(size_t)j * KX + k] = f2bf(v);
        }
        if (blk == 0) {
            for (int i = tid; i < 1664; i += 256) {
                if (i < 1600) cap_out[i] = (float)caps[i];
                else          len_out[i - 1600] = (float)(lens[i - 1600] - 1);
            }
        }
    } else if (blk < 2368) {
        int i = blk - 2048;
        int nb = (i % 40) * 64, kb = (i / 40) * 64;
        for (int s = 0; s < 4; ++s) {
            int k = kb + fy + s * 16;
            int n = nb + fx * 4;
            float4 v = (n < ATTD) ? *(const float4*)(Wd + (size_t)k * ATTD + n)
                                  : *(const float4*)(Wfb + (size_t)k * ENCD + (n - ATTD));
            tile[fy + s * 16][fx * 4 + 0] = v.x;
            tile[fy + s * 16][fx * 4 + 1] = v.y;
            tile[fy + s * 16][fx * 4 + 2] = v.z;
            tile[fy + s * 16][fx * 4 + 3] = v.w;
        }
        __syncthreads();
        for (int s = 0; s < 64; s += 4)
            BpreT[(size_t)(nb + ty + s) * 512 + kb + tx] = f2bf(tile[tx][ty + s]);
    } else if (blk < 3632) {
        int i = blk - 2368;
        int nb = (i % 158) * 64, kb = (i / 158) * 64;
        for (int s = 0; s < 4; ++s) {
            int k = kb + fy + s * 16;
            int n = nb + fx * 4;
            float4 v = make_float4(0.f, 0.f, 0.f, 0.f);
            if (n < NVOCAB) v = *(const float4*)(Wfc + (size_t)k * NVOCAB + n);
            tile[fy + s * 16][fx * 4 + 0] = v.x;
            tile[fy + s * 16][fx * 4 + 1] = v.y;
            tile[fy + s * 16][fx * 4 + 2] = v.z;
            tile[fy + s * 16][fx * 4 + 3] = v.w;
        }
        __syncthreads();
        for (int s = 0; s < 64; s += 4)
            WfcT[(size_t)(nb + ty + s) * 512 + kb + tx] = f2bf(tile[tx][ty + s]);
    } else if (blk < 3888) {
        int i = blk - 3632;
        int nb = (i % 8) * 64, kb = (i / 8) * 64;
        for (int s = 0; s < 4; ++s) {
            int k = kb + fy + s * 16;
            int n = nb + fx * 4;
            float4 v = *(const float4*)(We + (size_t)k * ATTD + n);
            tile[fy + s * 16][fx * 4 + 0] = v.x;
            tile[fy + s * 16][fx * 4 + 1] = v.y;
            tile[fy + s * 16][fx * 4 + 2] = v.z;
            tile[fy + s * 16][fx * 4 + 3] = v.w;
        }
        __syncthreads();
        for (int s = 0; s < 64; s += 4)
            WeT[(size_t)(nb + ty + s) * ENCD + kb + tx] = f2bf(tile[tx][ty + s]);
    } else if (blk < 4656) {
        int i = blk - 3888;
        int r0 = (i % 24) * 64;
        int n0 = (i / 24) * 64;
        int w = tid >> 6, l = tid & 63;
        int m = l & 15, kg = l >> 4;
        int n = n0 + w * 16 + m;
        const float* Bp = Wih + (size_t)n * 2560 + kg * 8;
        int tok[4];
#pragma unroll
        for (int mf = 0; mf < 4; ++mf) {
            int row = r0 + m + mf * 16;
            tok[mf] = caps[(row & 63) * 25 + (row >> 6)];
        }
        f32x4 acc[4] = {};
        for (int k0 = 0; k0 < 512; k0 += 32) {
            float4 b0 = *(const float4*)(Bp + k0);
            float4 b1 = *(const float4*)(Bp + k0 + 4);
            bf16x8 bb;
            bb[0] = f2bf(b0.x); bb[1] = f2bf(b0.y); bb[2] = f2bf(b0.z); bb[3] = f2bf(b0.w);
            bb[4] = f2bf(b1.x); bb[5] = f2bf(b1.y); bb[6] = f2bf(b1.z); bb[7] = f2bf(b1.w);
#pragma unroll
            for (int mf = 0; mf < 4; ++mf) {
                const float* ap = emb + (size_t)tok[mf] * 512 + kg * 8 + k0;
                float4 f0 = *(const float4*)ap;
                float4 f1 = *(const float4*)(ap + 4);
                bf16x8 a;
                a[0] = f2bf(f0.x); a[1] = f2bf(f0.y); a[2] = f2bf(f0.z); a[3] = f2bf(f0.w);
                a[4] = f2bf(f1.x); a[5] = f2bf(f1.y); a[6] = f2bf(f1.z); a[7] = f2bf(f1.w);
                acc[mf] = __builtin_amdgcn_mfma_f32_16x16x32_bf16(a, bb, acc[mf], 0, 0, 0);
            }
        }
#pragma unroll
        for (int mf = 0; mf < 4; ++mf)
#pragma unroll
            for (int r = 0; r < 4; ++r)
                embpartb[(size_t)(r0 + mf * 16 + kg * 4 + r) * 2048 + n] = f2bf(acc[mf][r]);
    } else {
        int i = blk - 4656;
        for (int j = tid; j < 2048; j += 256) hcacc[(size_t)i * 2048 + j] = 0.f;
    }
}

// ---------------- enc fp32 -> bf16 ----------------
__global__ void k_encconv(const float* __restrict__ enc, ushort* __restrict__ encb) {
    size_t i = ((size_t)blockIdx.x * 256 + threadIdx.x) * 8;
    float4 f0 = *(const float4*)(enc + i);
    float4 f1 = *(const float4*)(enc + i + 4);
    union { bf16x8 v; ushort u[8]; } o;
    o.u[0] = f2bf(f0.x); o.u[1] = f2bf(f0.y); o.u[2] = f2bf(f0.z); o.u[3] = f2bf(f0.w);
    o.u[4] = f2bf(f1.x); o.u[5] = f2bf(f1.y); o.u[6] = f2bf(f1.z); o.u[7] = f2bf(f1.w);
    *(bf16x8*)(encb + i) = o.v;
}

// ---------------- mean over 196 positions ----------------
__global__ __launch_bounds__(256) void k_meanb(const ushort* __restrict__ encb,
                                               ushort* __restrict__ meanb) {
    int b = blockIdx.x, half = blockIdx.y;
    int e0 = half * 1024 + threadIdx.x * 4;
    const ushort* ep = encb + (size_t)b * NPIX * ENCD + e0;
    float s0 = 0.f, s1 = 0.f, s2 = 0.f, s3 = 0.f;
#pragma unroll 4
    for (int p = 0; p < NPIX; ++p) {
        ushort4 v = *(const ushort4*)(ep + (size_t)p * ENCD);
        s0 += bf2f(v.x); s1 += bf2f(v.y); s2 += bf2f(v.z); s3 += bf2f(v.w);
    }
    const float sc = 1.0f / NPIX;
    ushort4 o;
    o.x = f2bf(s0 * sc); o.y = f2bf(s1 * sc); o.z = f2bf(s2 * sc); o.w = f2bf(s3 * sc);
    *(ushort4*)(meanb + (size_t)b * ENCD + e0) = o;
}

// ---------------- h0/c0 init partials ----------------
__global__ __launch_bounds__(256) void k_initp(
        const ushort* __restrict__ meanb,
        const float* __restrict__ Wh, const float* __restrict__ Wc,
        float* __restrict__ hcacc) {
    __shared__ float mm[4][256];
    int bg = blockIdx.x * 4;
    int jy = blockIdx.y;
    int kz = blockIdx.z;
    int tid = threadIdx.x;
    for (int i = tid; i < 1024; i += 256) {
        int qq = i >> 8, k = i & 255;
        mm[qq][k] = bf2f(meanb[(size_t)(bg + qq) * ENCD + kz * 256 + k]);
    }
    __syncthreads();
    int j = jy * 256 + tid;
    const float* W; int col;
    if (j < 512) { W = Wh; col = j; } else { W = Wc; col = j - 512; }
    W += (size_t)(kz * 256) * 512 + col;
    float acc[4] = {};
    for (int k = 0; k < 256; ++k) {
        float w = W[(size_t)k * 512];
#pragma unroll
        for (int qq = 0; qq < 4; ++qq) acc[qq] += mm[qq][k] * w;
    }
#pragma unroll
    for (int qq = 0; qq < 4; ++qq)
        atomicAdd(hcacc + (size_t)(bg + qq) * 1024 + j, acc[qq]);
}

__global__ __launch_bounds__(256) void k_initfin(
        const float* __restrict__ hcacc, const float* __restrict__ bh,
        const float* __restrict__ bc, ushort* __restrict__ hbf,
        float* __restrict__ c) {
    int base = blockIdx.x * 2048;
    for (int i = threadIdx.x; i < 2048; i += 256) {
        int idx = base + i;
        int b = idx >> 10, n = idx & 1023;
        float v = hcacc[idx];
        if (n < 512) hbf[(size_t)b * 512 + n] = f2bf(v + bh[n]);
        else         c[(size_t)b * 512 + (n - 512)] = v + bc[n - 512];
    }
}

// ---------------- one-time: att1 = enc @ We + be ----------------
// 128x128 tile + XCD swizzle + in-block K-split x2 (8 waves), LDS combine.
__global__ __launch_bounds__(512) void k_att1(
        const ushort* __restrict__ encb, const ushort* __restrict__ WeT,
        const float* __restrict__ be, ushort* __restrict__ att1b) {
    __shared__ float red[4][64][65];
    int bid = blockIdx.x;                       // 392 blocks
    int L = (bid & 7) * 49 + (bid >> 3);        // bijective; 4 n-tiles of one m share bid&7 (XCD)
    int mt = L >> 2, nt = L & 3;
    int tid = threadIdx.x;
    int w = tid >> 6, l = tid & 63;
    int q = w & 3, kh = w >> 2;
    int wr = q >> 1, wc = q & 1;
    int m0 = mt * 128 + wr * 64;
    int n0 = nt * 128 + wc * 64;
    int ml = l & 15, kg = l >> 4;
    const ushort* aBase = encb + (size_t)(m0 + ml) * ENCD + kh * 1024 + kg * 8;
    const ushort* bBase = WeT + (size_t)(n0 + ml) * ENCD + kh * 1024 + kg * 8;
    f32x4 acc[4][4] = {};
    for (int k0 = 0; k0 < 1024; k0 += 32) {
        bf16x8 bfr[4], afr[4];
#pragma unroll
        for (int nf = 0; nf < 4; ++nf)
            bfr[nf] = *(const bf16x8*)(bBase + (size_t)nf * 16 * ENCD + k0);
#pragma unroll
        for (int mf = 0; mf < 4; ++mf)
            afr[mf] = *(const bf16x8*)(aBase + (size_t)mf * 16 * ENCD + k0);
#pragma unroll
        for (int mf = 0; mf < 4; ++mf)
#pragma unroll
            for (int nf = 0; nf < 4; ++nf)
                acc[mf][nf] = __builtin_amdgcn_mfma_f32_16x16x32_bf16(afr[mf], bfr[nf], acc[mf][nf], 0, 0, 0);
    }
    if (kh == 1) {
#pragma unroll
        for (int mf = 0; mf < 4; ++mf)
#pragma unroll
            for (int nf = 0; nf < 4; ++nf)
#pragma unroll
                for (int r = 0; r < 4; ++r)
                    red[q][mf * 16 + kg * 4 + r][nf * 16 + ml] = acc[mf][nf][r];
    }
    __syncthreads();
    if (kh == 0) {
#pragma unroll
        for (int mf = 0; mf < 4; ++mf)
#pragma unroll
            for (int nf = 0; nf < 4; ++nf) {
                int col = n0 + nf * 16 + ml;
                float bias = be[col];
#pragma unroll
                for (int r = 0; r < 4; ++r) {
                    int row = m0 + mf * 16 + kg * 4 + r;
                    float v = acc[mf][nf][r] + red[q][mf * 16 + kg * 4 + r][nf * 16 + ml];
                    att1b[(size_t)row * ATTD + col] = f2bf(v + bias);
                }
            }
    }
}

// ---------------- per-step K1: att2 + gate MFMA (40 blocks, K-split 2) ----------------
__global__ __launch_bounds__(512) void k_hsmall2(
        const ushort* __restrict__ hb_cur, const ushort* __restrict__ BpreT,
        const float* __restrict__ bd, const float* __restrict__ bfb,
        float* __restrict__ att2, ushort* __restrict__ gateb) {
    __shared__ float part[2][64][68];
    int blk = blockIdx.x;
    int tid = threadIdx.x;
    int w = tid >> 6, l = tid & 63;
    int wq = w & 3, kh = w >> 2;
    int m = l & 15, kg = l >> 4;
    int n = blk * 64 + wq * 16 + m;
    const ushort* B = BpreT + (size_t)n * 512 + kh * 256 + kg * 8;
    const ushort* A = hb_cur + (size_t)m * 512 + kh * 256 + kg * 8;
    f32x4 acc[4] = {};
#pragma unroll
    for (int k0 = 0; k0 < 256; k0 += 32) {
        bf16x8 bfr = *(const bf16x8*)(B + k0);
#pragma unroll
        for (int mf = 0; mf < 4; ++mf) {
            bf16x8 afr = *(const bf16x8*)(A + mf * 16 * 512 + k0);
            acc[mf] = __builtin_amdgcn_mfma_f32_16x16x32_bf16(afr, bfr, acc[mf], 0, 0, 0);
        }
    }
#pragma unroll
    for (int mf = 0; mf < 4; ++mf)
#pragma unroll
        for (int r = 0; r < 4; ++r)
            part[kh][mf * 16 + kg * 4 + r][wq * 16 + m] = acc[mf][r];
    __syncthreads();
    for (int idx = tid; idx < 4096; idx += 512) {
        int b = idx >> 6, nn = idx & 63;
        float v = part[0][b][nn] + part[1][b][nn];
        int ng = blk * 64 + nn;
        if (ng < 512) att2[(size_t)b * 512 + ng] = v + bd[ng];
        else {
            int e = ng - 512;
            gateb[(size_t)b * 2048 + e] = f2bf(1.f / (1.f + __expf(-(v + bfb[e]))));
        }
    }
}

// ---------------- per-step K2: scores+softmax (x4) + ctx quarter (XCD swizzle, early-exit) ----------------
__global__ __launch_bounds__(512) void k_scorectx(
        const ushort* __restrict__ att1b, const float* __restrict__ att2,
        const float* __restrict__ vatt, const float* __restrict__ bv,
        const ushort* __restrict__ gateb, const int* __restrict__ lens,
        const ushort* __restrict__ encb,
        ushort* __restrict__ ctxb, float* __restrict__ alpha_out, int t) {
    __shared__ float ev[200];
    __shared__ float cpart[4][512];
    __shared__ float inv_s;
    int bid = blockIdx.x;
    // XCD-friendly: the 4 q-blocks of a given b share bid%8 -> same XCD L2
    int b = ((bid & 7) << 3) | ((bid >> 3) & 7);
    int q = bid >> 6;
    int tid = threadIdx.x;
    int w = tid >> 6, l = tid & 63;
    // inactive row: only alpha zeros needed (t=0 active for all b, so ctxb never stale-poisoned)
    if (t >= lens[b] - 1) {
        if (q == 0 && tid < NPIX)
            alpha_out[((size_t)b * TSTEPS + t) * NPIX + tid] = 0.f;
        return;
    }
    {
        float a2r[8], vvr[8];
        const float* att2b = att2 + (size_t)b * ATTD;
#pragma unroll
        for (int i = 0; i < 8; ++i) {
            a2r[i] = att2b[l * 8 + i];
            vvr[i] = vatt[l * 8 + i];
        }
        float bv0 = bv[0];
        for (int pp = w; pp < NPIX; pp += 8) {
            bf16x8 f = *(const bf16x8*)(att1b + ((size_t)b * NPIX + pp) * ATTD + l * 8);
            float s = 0.f;
#pragma unroll
            for (int i = 0; i < 8; ++i)
                s += fmaxf(bf2f((ushort)f[i]) + a2r[i], 0.f) * vvr[i];
            for (int off = 32; off > 0; off >>= 1) s += __shfl_down(s, off);
            if (l == 0) ev[pp] = s + bv0;
        }
    }
    __syncthreads();
    if (w == 0) {
        float mx = -1e30f;
        for (int pp = l; pp < NPIX; pp += 64) mx = fmaxf(mx, ev[pp]);
        for (int off = 32; off > 0; off >>= 1) mx = fmaxf(mx, __shfl_down(mx, off));
        mx = __shfl(mx, 0);
        float s = 0.f;
        for (int pp = l; pp < NPIX; pp += 64) {
            float e_ = __expf(ev[pp] - mx);
            ev[pp] = e_;
            s += e_;
        }
        for (int off = 32; off > 0; off >>= 1) s += __shfl_down(s, off);
        if (l == 0) inv_s = 1.0f / s;
    }
    __syncthreads();
    float inv = inv_s;
    if (q == 0 && tid < NPIX)
        alpha_out[((size_t)b * TSTEPS + t) * NPIX + tid] = ev[tid] * inv;
    {
        int pg = tid >> 7, th = tid & 127;
        const ushort* ep = encb + (size_t)b * NPIX * ENCD + q * 512 + th * 4;
        float s0 = 0.f, s1 = 0.f, s2 = 0.f, s3 = 0.f;
        for (int pp = pg; pp < NPIX; pp += 4) {
            ushort4 v = *(const ushort4*)(ep + (size_t)pp * ENCD);
            float al = ev[pp];
            s0 += al * bf2f(v.x); s1 += al * bf2f(v.y);
            s2 += al * bf2f(v.z); s3 += al * bf2f(v.w);
        }
        cpart[pg][th * 4 + 0] = s0;
        cpart[pg][th * 4 + 1] = s1;
        cpart[pg][th * 4 + 2] = s2;
        cpart[pg][th * 4 + 3] = s3;
    }
    __syncthreads();
    if (tid < 128) {
        ushort4 g4 = *(const ushort4*)(gateb + (size_t)b * 2048 + q * 512 + tid * 4);
        ushort4 o;
        o.x = f2bf((cpart[0][tid * 4 + 0] + cpart[1][tid * 4 + 0] + cpart[2][tid * 4 + 0] + cpart[3][tid * 4 + 0]) * inv * bf2f(g4.x));
        o.y = f2bf((cpart[0][tid * 4 + 1] + cpart[1][tid * 4 + 1] + cpart[2][tid * 4 + 1] + cpart[3][tid * 4 + 1]) * inv * bf2f(g4.y));
        o.z = f2bf((cpart[0][tid * 4 + 2] + cpart[1][tid * 4 + 2] + cpart[2][tid * 4 + 2] + cpart[3][tid * 4 + 2]) * inv * bf2f(g4.z));
        o.w = f2bf((cpart[0][tid * 4 + 3] + cpart[1][tid * 4 + 3] + cpart[2][tid * 4 + 3] + cpart[3][tid * 4 + 3]) * inv * bf2f(g4.w));
        *(ushort4*)(ctxb + (size_t)b * 2048 + q * 512 + tid * 4) = o;
    }
}

// ---------------- per-step K3: gates GEMM (128 blocks, balanced 8-wave K-split) + LSTM ----------------
__global__ __launch_bounds__(512) void k_gates2(
        const ushort* __restrict__ ctxb, const ushort* __restrict__ hb_cur,
        const ushort* __restrict__ WTj, const ushort* __restrict__ embpartb,
        const float* __restrict__ bih, const float* __restrict__ bhh,
        const int* __restrict__ lens, float* __restrict__ c,
        ushort* __restrict__ hb_nxt, ushort* __restrict__ hAll, int t) {
    __shared__ float part[8][64][16];
    int g = blockIdx.x;
    int tid = threadIdx.x;
    int w = tid >> 6, l = tid & 63;
    int m = l & 15, kg = l >> 4;
    int jrow = (m >> 2) * 512 + g * 4 + (m & 3);
    const ushort* Brow = WTj + (size_t)jrow * KX;
    f32x4 acc[4] = {};
    {
        const ushort* B = Brow + 512 + w * 256 + kg * 8;
        const ushort* A = ctxb + (size_t)m * 2048 + w * 256 + kg * 8;
#pragma unroll
        for (int k0 = 0; k0 < 256; k0 += 32) {
            bf16x8 bfr = *(const bf16x8*)(B + k0);
#pragma unroll
            for (int mf = 0; mf < 4; ++mf) {
                bf16x8 afr = *(const bf16x8*)(A + (size_t)mf * 16 * 2048 + k0);
                acc[mf] = __builtin_amdgcn_mfma_f32_16x16x32_bf16(afr, bfr, acc[mf], 0, 0, 0);
            }
        }
    }
    {
        const ushort* B = Brow + 2560 + w * 64 + kg * 8;
        const ushort* A = hb_cur + (size_t)m * 512 + w * 64 + kg * 8;
#pragma unroll
        for (int k0 = 0; k0 < 64; k0 += 32) {
            bf16x8 bfr = *(const bf16x8*)(B + k0);
#pragma unroll
            for (int mf = 0; mf < 4; ++mf) {
                bf16x8 afr = *(const bf16x8*)(A + (size_t)mf * 16 * 512 + k0);
                acc[mf] = __builtin_amdgcn_mfma_f32_16x16x32_bf16(afr, bfr, acc[mf], 0, 0, 0);
            }
        }
    }
#pragma unroll
    for (int mf = 0; mf < 4; ++mf)
#pragma unroll
        for (int r = 0; r < 4; ++r)
            part[w][mf * 16 + kg * 4 + r][m] = acc[mf][r];
    __syncthreads();
    if (tid < 256) {
        int bb = tid >> 2, j = tid & 3;
        int d = g * 4 + j;
        float gi = 0.f, gf = 0.f, gg = 0.f, go = 0.f;
#pragma unroll
        for (int w8 = 0; w8 < 8; ++w8) {
            gi += part[w8][bb][j];
            gf += part[w8][bb][4 + j];
            gg += part[w8][bb][8 + j];
            go += part[w8][bb][12 + j];
        }
        ushort hout = hb_cur[(size_t)bb * 512 + d];
        if (t < lens[bb] - 1) {
            const ushort* eb = embpartb + ((size_t)t * 64 + bb) * 2048;
            gi += bf2f(eb[d])        + bih[d]        + bhh[d];
            gf += bf2f(eb[512 + d])  + bih[512 + d]  + bhh[512 + d];
            gg += bf2f(eb[1024 + d]) + bih[1024 + d] + bhh[1024 + d];
            go += bf2f(eb[1536 + d]) + bih[1536 + d] + bhh[1536 + d];
            float cc = c[(size_t)bb * 512 + d];
            float si = 1.f / (1.f + __expf(-gi));
            float sf = 1.f / (1.f + __expf(-gf));
            float so = 1.f / (1.f + __expf(-go));
            float cn = sf * cc + si * tanhf(gg);
            float hn = so * tanhf(cn);
            c[(size_t)bb * 512 + d] = cn;
            hout = f2bf(hn);
        }
        hb_nxt[(size_t)bb * 512 + d] = hout;
        hAll[((size_t)t * 64 + bb) * 512 + d] = hout;
    }
}

// ---------------- post-loop: pred = hAll @ WfcT + bfc (masked) ----------------
__global__ __launch_bounds__(256) void k_predall(
        const ushort* __restrict__ hAll, const ushort* __restrict__ WfcT,
        const float* __restrict__ bfc, const int* __restrict__ lens,
        float* __restrict__ pred) {
    int w = threadIdx.x >> 6, l = threadIdx.x & 63;
    int wr = w >> 1, wc = w & 1;
    int m0 = blockIdx.x * 128 + wr * 64;
    int n0 = blockIdx.y * 128 + wc * 64;
    int ml = l & 15, kg = l >> 4;
    const ushort* aBase = hAll + (size_t)(m0 + ml) * 512 + kg * 8;
    const ushort* bBase = WfcT + (size_t)(n0 + ml) * 512 + kg * 8;
    f32x4 acc[4][4] = {};
#pragma unroll 2
    for (int k0 = 0; k0 < 512; k0 += 32) {
        bf16x8 bfr[4], afr[4];
#pragma unroll
        for (int nf = 0; nf < 4; ++nf)
            bfr[nf] = *(const bf16x8*)(bBase + (size_t)nf * 16 * 512 + k0);
#pragma unroll
        for (int mf = 0; mf < 4; ++mf)
            afr[mf] = *(const bf16x8*)(aBase + (size_t)mf * 16 * 512 + k0);
#pragma unroll
        for (int mf = 0; mf < 4; ++mf)
#pragma unroll
            for (int nf = 0; nf < 4; ++nf)
                acc[mf][nf] = __builtin_amdgcn_mfma_f32_16x16x32_bf16(afr[mf], bfr[nf], acc[mf][nf], 0, 0, 0);
    }
#pragma unroll
    for (int mf = 0; mf < 4; ++mf)
#pragma unroll
        for (int nf = 0; nf < 4; ++nf) {
            int col = n0 + nf * 16 + ml;
            if (col < NVOCAB) {
                float bias = bfc[col];
#pragma unroll
                for (int r = 0; r < 4; ++r) {
                    int row = m0 + mf * 16 + kg * 4 + r;
                    int t = row >> 6, b = row & 63;
                    bool act = t < (lens[b] - 1);
                    pred[((size_t)b * TSTEPS + t) * NVOCAB + col] = act ? acc[mf][nf][r] + bias : 0.f;
                }
            }
        }
}

extern "C" void kernel_launch(void* const* d_in, const int* in_sizes, int n_in,
                              void* d_out, int out_size, void* d_ws, size_t ws_size,
                              hipStream_t stream) {
    const float* enc  = (const float*)d_in[0];
    const int*   caps = (const int*)d_in[1];
    const int*   lens = (const int*)d_in[2];
    const float* emb  = (const float*)d_in[3];
    const float* We   = (const float*)d_in[4];
    const float* be   = (const float*)d_in[5];
    const float* Wd   = (const float*)d_in[6];
    const float* bd   = (const float*)d_in[7];
    const float* vatt = (const float*)d_in[8];
    const float* bv   = (const float*)d_in[9];
    const float* Wih  = (const float*)d_in[10];
    const float* bih  = (const float*)d_in[11];
    const float* Whh  = (const float*)d_in[12];
    const float* bhh  = (const float*)d_in[13];
    const float* Winh = (const float*)d_in[14];
    const float* binh = (const float*)d_in[15];
    const float* Winc = (const float*)d_in[16];
    const float* binc = (const float*)d_in[17];
    const float* Wfb  = (const float*)d_in[18];
    const float* bfb  = (const float*)d_in[19];
    const float* Wfc  = (const float*)d_in[20];
    const float* bfc  = (const float*)d_in[21];

    float* out       = (float*)d_out;
    float* pred_out  = out;
    float* cap_out   = out + 15360000;
    float* len_out   = out + 15361600;
    float* alpha_out = out + 15361664;

    char* p = (char*)d_ws;
    ushort* att1b    = (ushort*)p; p += (size_t)12544 * 512 * 2;
    ushort* WTj      = (ushort*)p; p += (size_t)2048 * KX * 2;
    ushort* WfcT     = (ushort*)p; p += (size_t)NPAD * 512 * 2;
    ushort* BpreT    = (ushort*)p; p += (size_t)2560 * 512 * 2;
    ushort* WeT      = (ushort*)p; p += (size_t)512 * 2048 * 2;
    ushort* embpartb = (ushort*)p; p += (size_t)1536 * 2048 * 2;
    ushort* hAll     = (ushort*)p; p += (size_t)1536 * 512 * 2;
    ushort* ctxb     = (ushort*)p; p += (size_t)64 * 2048 * 2;   // aliased: hcacc
    ushort* hb0      = (ushort*)p; p += (size_t)64 * 512 * 2;
    ushort* hb1      = (ushort*)p; p += (size_t)64 * 512 * 2;
    float* c         = (float*)p;  p += (size_t)64 * 512 * 4;
    ushort* meanb    = (ushort*)p; p += (size_t)64 * 2048 * 2;
    float* att2      = (float*)p;  p += (size_t)64 * 512 * 4;
    ushort* gateb    = (ushort*)p; p += (size_t)64 * 2048 * 2;
    ushort* encb     = (ushort*)p; p += (size_t)64 * NPIX * ENCD * 2;
    float* hcacc     = (float*)ctxb;

    k_prep<<<4688, 256, 0, stream>>>(Wih, Whh, Wd, Wfb, Wfc, We, emb, caps, lens,
                                     WTj, BpreT, WfcT, WeT, embpartb, hcacc,
                                     cap_out, len_out);
    k_encconv<<<12544, 256, 0, stream>>>(enc, encb);
    k_meanb<<<dim3(64, 2), 256, 0, stream>>>(encb, meanb);
    k_initp<<<dim3(16, 4, 8), 256, 0, stream>>>(meanb, Winh, Winc, hcacc);
    k_initfin<<<32, 256, 0, stream>>>(hcacc, binh, binc, hb0, c);
    k_att1<<<392, 512, 0, stream>>>(encb, WeT, be, att1b);

    for (int t = 0; t < TSTEPS; ++t) {
        const ushort* hcur = (t & 1) ? hb1 : hb0;
        ushort* hnxt = (t & 1) ? hb0 : hb1;
        k_hsmall2<<<40, 512, 0, stream>>>(hcur, BpreT, bd, bfb, att2, gateb);
        k_scorectx<<<256, 512, 0, stream>>>(att1b, att2, vatt, bv, gateb, lens,
                                            encb, ctxb, alpha_out, t);
        k_gates2<<<128, 512, 0, stream>>>(ctxb, hcur, WTj, embpartb, bih, bhh,
                                          lens, c, hnxt, hAll, t);
    }
    k_predall<<<dim3(12, 79), 256, 0, stream>>>(hAll, WfcT, bfc, lens, pred_out);
}